// Round 1
// baseline (1129.071 us; speedup 1.0000x reference)
//
#include <hip/hip_runtime.h>
#include <hip/hip_bf16.h>

// ---------------------------------------------------------------------------
// TitansMemory: B=2, L=1024, D=M=2048, P=8, Kconv=4.
// Strategy: all matmuls as bf16 NT-GEMM (MFMA 16x16x32), fp32 accumulate.
// NN-shaped products feed a transposed-converted B operand.
// Attention materialized with padded width 1152 (zero rows masked out).
// ---------------------------------------------------------------------------

#define NROWS 2048      // B*L
#define MD    2048      // D == M
#define PL    1032      // P + L
#define PLP   1152      // padded to multiple of 128

using bf16x8 = __attribute__((ext_vector_type(8))) __bf16;
using f32x4  = __attribute__((ext_vector_type(4))) float;

__device__ __forceinline__ unsigned short f2bf(float f) {
    union { float f; unsigned int u; } c; c.f = f;
    unsigned int u = c.u;
    return (unsigned short)((u + 0x7fffu + ((u >> 16) & 1u)) >> 16);
}
__device__ __forceinline__ float bf2f(unsigned short h) {
    union { float f; unsigned int u; } c; c.u = ((unsigned int)h) << 16;
    return c.f;
}
__device__ __forceinline__ float ldf(const float* p) { return *p; }
__device__ __forceinline__ float ldf(const unsigned short* p) { return bf2f(*p); }
__device__ __forceinline__ float sigm(float x) { return 1.f / (1.f + __expf(-x)); }
__device__ __forceinline__ float silu(float x) { return x / (1.f + __expf(-x)); }

__device__ __forceinline__ float block_reduce_sum(float v) {
    __shared__ float ws[4];
    #pragma unroll
    for (int o = 32; o > 0; o >>= 1) v += __shfl_down(v, o);
    __syncthreads();
    if ((threadIdx.x & 63) == 0) ws[threadIdx.x >> 6] = v;
    __syncthreads();
    return (ws[0] + ws[1]) + (ws[2] + ws[3]);
}
__device__ __forceinline__ float block_reduce_max(float v) {
    __shared__ float wm[4];
    #pragma unroll
    for (int o = 32; o > 0; o >>= 1) v = fmaxf(v, __shfl_down(v, o));
    __syncthreads();
    if ((threadIdx.x & 63) == 0) wm[threadIdx.x >> 6] = v;
    __syncthreads();
    return fmaxf(fmaxf(wm[0], wm[1]), fmaxf(wm[2], wm[3]));
}

// ---------------- NT GEMM: C[n,m] (+)= sum_k A[n,k]*B[m,k], bf16 in fp32 out.
// 128x128 tile, 4 waves in 2x2, each wave 4x4 tiles of 16x16x32 MFMA.
__global__ __launch_bounds__(256) void gemm_nt(
    const unsigned short* __restrict__ A, const unsigned short* __restrict__ Bm,
    float* __restrict__ C, int N, int Mc, int K,
    long sA, long sB, long sC, int beta)
{
    __shared__ unsigned short As[128][72];   // +8 pad: 2-way LDS aliasing only
    __shared__ unsigned short Bs[128][72];
    const unsigned short* Ap = A + (size_t)blockIdx.z * sA;
    const unsigned short* Bp = Bm + (size_t)blockIdx.z * sB;
    float* Cp = C + (size_t)blockIdx.z * sC;
    const int tid = threadIdx.x;
    const int lane = tid & 63, w = tid >> 6;
    const int wm = w >> 1, wn = w & 1;
    const int l16 = lane & 15, quad = lane >> 4;
    const size_t rowBase = (size_t)blockIdx.y * 128;
    const size_t colBase = (size_t)blockIdx.x * 128;

    f32x4 acc[4][4] = {};

    for (int k0 = 0; k0 < K; k0 += 64) {
        #pragma unroll
        for (int t = 0; t < 4; ++t) {
            int idx = t * 256 + tid;
            int r = idx >> 3, c8 = (idx & 7) * 8;
            *(int4*)&As[r][c8] = *(const int4*)&Ap[(rowBase + r) * K + k0 + c8];
            *(int4*)&Bs[r][c8] = *(const int4*)&Bp[(colBase + r) * K + k0 + c8];
        }
        __syncthreads();
        #pragma unroll
        for (int ks = 0; ks < 2; ++ks) {
            bf16x8 af[4], bfr[4];
            #pragma unroll
            for (int i = 0; i < 4; ++i)
                af[i] = *(const bf16x8*)&As[wm * 64 + i * 16 + l16][ks * 32 + quad * 8];
            #pragma unroll
            for (int j = 0; j < 4; ++j)
                bfr[j] = *(const bf16x8*)&Bs[wn * 64 + j * 16 + l16][ks * 32 + quad * 8];
            #pragma unroll
            for (int i = 0; i < 4; ++i)
                #pragma unroll
                for (int j = 0; j < 4; ++j)
                    acc[i][j] = __builtin_amdgcn_mfma_f32_16x16x32_bf16(af[i], bfr[j], acc[i][j], 0, 0, 0);
        }
        __syncthreads();
    }
    // C/D layout (m89/m91-verified): col = lane&15, row = quad*4 + reg
    #pragma unroll
    for (int i = 0; i < 4; ++i)
        #pragma unroll
        for (int r = 0; r < 4; ++r) {
            size_t gr = rowBase + wm * 64 + i * 16 + quad * 4 + r;
            #pragma unroll
            for (int j = 0; j < 4; ++j) {
                size_t gc = colBase + wn * 64 + j * 16 + l16;
                size_t off = gr * (size_t)Mc + gc;
                if (beta) Cp[off] += acc[i][j][r]; else Cp[off] = acc[i][j][r];
            }
        }
}

// ---------------- tiled transpose + convert to bf16: dst[c*dstLd + dstOff + r] = src[r*C + c]
template <typename TS>
__global__ void transpose_to_bf16(const TS* __restrict__ src, unsigned short* __restrict__ dst,
                                  int R, int C, int dstLd, int dstOff)
{
    __shared__ float tile[32][33];
    int c0 = blockIdx.x * 32, r0 = blockIdx.y * 32;
    int tx = threadIdx.x, ty = threadIdx.y;     // 32 x 8
    #pragma unroll
    for (int i = 0; i < 4; ++i) {
        int r = r0 + ty + i * 8;
        tile[ty + i * 8][tx] = ldf(&src[(size_t)r * C + c0 + tx]);
    }
    __syncthreads();
    #pragma unroll
    for (int i = 0; i < 4; ++i) {
        int c = c0 + ty + i * 8;
        dst[(size_t)c * dstLd + dstOff + r0 + tx] = f2bf(tile[tx][ty + i * 8]);
    }
}

// ---------------- elementwise / small kernels ----------------
__global__ void k_f32_to_bf16(const float* __restrict__ in, unsigned short* __restrict__ o, int n) {
    int i = blockIdx.x * 256 + threadIdx.x;
    if (i < n) o[i] = f2bf(in[i]);
}
__global__ void k_silu_f32(const float* __restrict__ in, float* __restrict__ o, int n) {
    int i = blockIdx.x * 256 + threadIdx.x;
    if (i < n) o[i] = silu(in[i]);
}
__global__ void k_silu_bf16(const float* __restrict__ in, unsigned short* __restrict__ o, int n) {
    int i = blockIdx.x * 256 + threadIdx.x;
    if (i < n) o[i] = f2bf(silu(in[i]));
}
__global__ void k_sub(const float* __restrict__ a, const float* __restrict__ b,
                      float* __restrict__ o, int n) {
    int i = blockIdx.x * 256 + threadIdx.x;
    if (i < n) o[i] = a[i] - b[i];
}
// snapshot = (1-alpha)*mem + eta*sur + theta*mom/(B*L);  mom arrives in t (in-place)
__global__ void k_snap(float* __restrict__ t, const float* __restrict__ mem,
                       const float* __restrict__ sur, const float* __restrict__ scal, int n) {
    int i = blockIdx.x * 256 + threadIdx.x;
    if (i < n) {
        float eta = scal[0], theta = scal[1], alpha = scal[2];
        t[i] = (1.f - alpha) * mem[i] + eta * sur[i] + theta * t[i] * (1.f / 2048.f);
    }
}
__global__ void k_gate(const float* __restrict__ pre, const float* __restrict__ gb,
                       const float* __restrict__ ret, unsigned short* __restrict__ o, int n) {
    int i = blockIdx.x * 256 + threadIdx.x;
    if (i < n) {
        int m = i & (MD - 1);
        o[i] = f2bf(sigm(pre[i] + gb[m]) * ret[i]);
    }
}
// depthwise causal conv (K=4) + bf16 convert. xin: [B*L, M]
__global__ void k_dwconv(const float* __restrict__ xin, const float* __restrict__ dw,
                         unsigned short* __restrict__ o) {
    long i = (long)blockIdx.x * 256 + threadIdx.x;   // over B*L*M
    int m = (int)(i & (MD - 1));
    long n = i >> 11;
    int l = (int)(n & 1023);
    float s = 0.f;
    #pragma unroll
    for (int j = 0; j < 4; ++j) {
        int dl = j - 3;
        if (l + dl >= 0) s += dw[m * 4 + j] * xin[i + (long)dl * MD];
    }
    o[i] = f2bf(s);
}
// silu + l2-normalize a 2048-wide row, emit bf16
__global__ void k_silu_l2n(const float* __restrict__ in, unsigned short* __restrict__ o) {
    int n = blockIdx.x;
    const float* row = in + (size_t)n * MD;
    int t = threadIdx.x;
    float v[8]; float ss = 0.f;
    #pragma unroll
    for (int s = 0; s < 8; ++s) { float y = silu(row[t + s * 256]); v[s] = y; ss += y * y; }
    ss = block_reduce_sum(ss);
    float inv = 1.f / (sqrtf(ss) + 1e-6f);
    #pragma unroll
    for (int s = 0; s < 8; ++s) o[(size_t)n * MD + t + s * 256] = f2bf(v[s] * inv);
}
// x_pooled dot {eta,theta,alpha}_w accumulated via atomics. dots[i*2+b]
__global__ void k_pooled(const float* __restrict__ x, const float* __restrict__ ew,
                         const float* __restrict__ tw, const float* __restrict__ aw,
                         float* __restrict__ dots) {
    int b = blockIdx.y;
    size_t base = (size_t)b * 1024 * MD;
    size_t start = (size_t)blockIdx.x * 8192;
    float s0 = 0, s1 = 0, s2 = 0;
    for (int s = 0; s < 32; ++s) {
        size_t f = start + threadIdx.x + (size_t)s * 256;
        float xv = x[base + f];
        int d = (int)(f & (MD - 1));
        s0 += xv * ew[d]; s1 += xv * tw[d]; s2 += xv * aw[d];
    }
    s0 = block_reduce_sum(s0);
    if (threadIdx.x == 0) atomicAdd(&dots[0 * 2 + b], s0);
    s1 = block_reduce_sum(s1);
    if (threadIdx.x == 0) atomicAdd(&dots[1 * 2 + b], s1);
    s2 = block_reduce_sum(s2);
    if (threadIdx.x == 0) atomicAdd(&dots[2 * 2 + b], s2);
}
__global__ void k_scal_fin(const float* __restrict__ dots, const float* __restrict__ eb,
                           const float* __restrict__ tb, const float* __restrict__ ab,
                           float* __restrict__ scal) {
    if (threadIdx.x == 0 && blockIdx.x == 0) {
        const float invL = 1.f / 1024.f;
        float e = 0, th = 0, al = 0;
        for (int b = 0; b < 2; ++b) {
            e  += sigm(dots[0 + b] * invL + eb[0]);
            th += sigm(dots[2 + b] * invL + tb[0]);
            al += sigm(dots[4 + b] * invL + ab[0]);
        }
        scal[0] = e * 0.5f; scal[1] = th * 0.5f; scal[2] = al * 0.5f;
    }
}
// l2n(pk) -> kwp rows [0,P) for both batches
__global__ void k_pkn(const float* __restrict__ pk, unsigned short* __restrict__ kwp) {
    int p = blockIdx.x;
    int t = threadIdx.x;
    float v[8]; float ss = 0.f;
    #pragma unroll
    for (int s = 0; s < 8; ++s) { float y = pk[p * MD + t + s * 256]; v[s] = y; ss += y * y; }
    ss = block_reduce_sum(ss);
    float inv = 1.f / (sqrtf(ss) + 1e-6f);
    #pragma unroll
    for (int s = 0; s < 8; ++s) {
        unsigned short h = f2bf(v[s] * inv);
        kwp[(size_t)p * MD + t + s * 256] = h;
        kwp[(size_t)PLP * MD + (size_t)p * MD + t + s * 256] = h;
    }
}
__global__ void k_copy_k_kwp(const unsigned short* __restrict__ kb, unsigned short* __restrict__ kwp) {
    long i = (long)blockIdx.x * 256 + threadIdx.x;    // 2*1024*2048
    int m = (int)(i & (MD - 1));
    long n = i >> 11;
    int l = (int)(n & 1023); int b = (int)(n >> 10);
    kwp[((size_t)b * PLP + 8 + l) * MD + m] = kb[i];
}
__global__ void k_zero_kwp_tail(unsigned short* __restrict__ kwp) {
    long i = (long)blockIdx.x * 256 + threadIdx.x;    // 2*120*2048
    int m = (int)(i & (MD - 1));
    long r = i >> 11;
    int j = PL + (int)(r % 120); int b = (int)(r / 120);
    kwp[((size_t)b * PLP + j) * MD + m] = 0;
}
__global__ void k_pv_vwpT(const float* __restrict__ pv, unsigned short* __restrict__ vwpT) {
    long i = (long)blockIdx.x * 256 + threadIdx.x;    // 2048*8
    int pp = (int)(i & 7); int m = (int)(i >> 3);
    unsigned short h = f2bf(pv[pp * MD + m]);
    vwpT[(size_t)m * PLP + pp] = h;
    vwpT[(size_t)MD * PLP + (size_t)m * PLP + pp] = h;
}
__global__ void k_zero_vwpT_tail(unsigned short* __restrict__ vwpT) {
    long i = (long)blockIdx.x * 256 + threadIdx.x;    // 2*2048*120
    int pp = PL + (int)(i % 120);
    long bm = i / 120;
    vwpT[(size_t)bm * PLP + pp] = 0;
}
// masked softmax over padded width; writes bf16 attn (0 where masked)
__global__ void k_softmax(const float* __restrict__ S, unsigned short* __restrict__ attn) {
    int l = blockIdx.x, b = blockIdx.y;
    size_t base = ((size_t)b * 1024 + l) * PLP;
    int nvis = 8 + l + 1;
    const float scale = 0.022097086912079608f;  // 1/sqrt(2048)
    int t = threadIdx.x;
    float vals[5];
    float mx = -1e30f;
    #pragma unroll
    for (int s = 0; s < 5; ++s) {
        int j = t + s * 256;
        float v = -1e30f;
        if (j < nvis) v = S[base + j] * scale;
        vals[s] = v;
        mx = fmaxf(mx, v);
    }
    mx = block_reduce_max(mx);
    float sum = 0.f;
    #pragma unroll
    for (int s = 0; s < 5; ++s) {
        int j = t + s * 256;
        float e = 0.f;
        if (j < nvis) e = __expf(vals[s] - mx);
        vals[s] = e; sum += e;
    }
    sum = block_reduce_sum(sum);
    float inv = 1.f / sum;
    #pragma unroll
    for (int s = 0; s < 5; ++s) {
        int j = t + s * 256;
        if (j < PLP) attn[base + j] = f2bf(vals[s] * inv);
    }
}
// out = RMSNorm(x + y) * ln_w
__global__ void k_final(const float* __restrict__ x, const float* __restrict__ y,
                        const float* __restrict__ lnw, float* __restrict__ out) {
    int n = blockIdx.x;
    size_t base = (size_t)n * MD;
    int t = threadIdx.x;
    float v[8]; float ss = 0.f;
    #pragma unroll
    for (int s = 0; s < 8; ++s) {
        float o = x[base + t + s * 256] + y[base + t + s * 256];
        v[s] = o; ss += o * o;
    }
    ss = block_reduce_sum(ss);
    float inv = rsqrtf(ss * (1.f / 2048.f) + 1e-6f);
    #pragma unroll
    for (int s = 0; s < 8; ++s)
        out[base + t + s * 256] = v[s] * inv * lnw[t + s * 256];
}

// ---------------- host-side launch helper ----------------
static inline void gemm(hipStream_t st, const void* A, const void* B, float* C,
                        int N, int Mc, int K, long sA, long sB, long sC, int z, int beta) {
    dim3 g(Mc / 128, N / 128, z);
    hipLaunchKernelGGL(gemm_nt, g, dim3(256), 0, st,
                       (const unsigned short*)A, (const unsigned short*)B, C,
                       N, Mc, K, sA, sB, sC, beta);
}

extern "C" void kernel_launch(void* const* d_in, const int* in_sizes, int n_in,
                              void* d_out, int out_size, void* d_ws, size_t ws_size,
                              hipStream_t stream) {
    const float* x    = (const float*)d_in[0];
    const float* Wq   = (const float*)d_in[1];
    const float* Wk   = (const float*)d_in[2];
    const float* Wv   = (const float*)d_in[3];
    const float* qdw  = (const float*)d_in[4];
    const float* kdw  = (const float*)d_in[5];
    const float* vdw  = (const float*)d_in[6];
    const float* qpw  = (const float*)d_in[7];
    const float* kpw  = (const float*)d_in[8];
    const float* vpw  = (const float*)d_in[9];
    const float* pk   = (const float*)d_in[10];
    const float* pv   = (const float*)d_in[11];
    const float* mw1  = (const float*)d_in[12];
    const float* mw2  = (const float*)d_in[13];
    const float* etaw = (const float*)d_in[14];
    const float* etab = (const float*)d_in[15];
    const float* thw  = (const float*)d_in[16];
    const float* thb  = (const float*)d_in[17];
    const float* alw  = (const float*)d_in[18];
    const float* alb  = (const float*)d_in[19];
    const float* gw   = (const float*)d_in[20];
    const float* gb   = (const float*)d_in[21];
    const float* ow   = (const float*)d_in[22];
    const float* lnw  = (const float*)d_in[23];
    const float* mem  = (const float*)d_in[24];
    const float* sur  = (const float*)d_in[25];
    float* out = (float*)d_out;

    char* ws = (char*)d_ws;
    float* dots = (float*)ws;            // 6 floats
    float* scal = (float*)(ws + 1024);   // 3 floats
    size_t cur = 4096;
    auto take = [&](size_t bytes) -> char* {
        char* p = ws + cur; cur += (bytes + 255) & ~(size_t)255; return p;
    };
    const size_t NM  = (size_t)NROWS * MD;          // 4,194,304
    unsigned short* x_bf   = (unsigned short*)take(NM * 2);
    unsigned short* w_bf   = (unsigned short*)take(NM * 2);   // weight slot (reused)
    unsigned short* qc_bf  = (unsigned short*)take(NM * 2);   // conv/mlp/ret bf16 (reused)
    unsigned short* q_bf   = (unsigned short*)take(NM * 2);
    unsigned short* k_bf   = (unsigned short*)take(NM * 2);
    unsigned short* kT_bf  = (unsigned short*)take(NM * 2);
    unsigned short* eT_bf  = (unsigned short*)take(NM * 2);   // err^T
    unsigned short* sT_bf  = (unsigned short*)take(NM * 2);   // snapshot^T
    unsigned short* g_bf   = (unsigned short*)take(NM * 2);   // gate*ret
    unsigned short* kwp    = (unsigned short*)take((size_t)2 * PLP * MD * 2);
    unsigned short* vwpT   = (unsigned short*)take((size_t)2 * MD * PLP * 2);
    float* t0  = (float*)take(NM * 4);
    float* t1  = (float*)take(NM * 4);
    float* vf  = (float*)take(NM * 4);
    float* ret = (float*)take(NM * 4);

    const int n4M = (int)NM;                 // 4,194,304
    const dim3 b256(256);
    const dim3 gEl(n4M / 256);               // 16384 blocks
    const dim3 gT(64, 64), bT(32, 8);

    // -- scalars eta/theta/alpha
    hipMemsetAsync(dots, 0, 256, stream);
    hipLaunchKernelGGL(k_pooled, dim3(256, 2), b256, 0, stream, x, etaw, thw, alw, dots);
    hipLaunchKernelGGL(k_scal_fin, dim3(1), dim3(64), 0, stream, dots, etab, thb, alb, scal);

    // -- x to bf16
    hipLaunchKernelGGL(k_f32_to_bf16, gEl, b256, 0, stream, x, x_bf, n4M);

    // -- q / k / v branches: proj GEMM -> dwconv -> pw GEMM -> silu(+l2n)
    const float* Wp[3]  = {Wq, Wk, Wv};
    const float* dwp[3] = {qdw, kdw, vdw};
    const float* pwp[3] = {qpw, kpw, vpw};
    for (int br = 0; br < 3; ++br) {
        hipLaunchKernelGGL(k_f32_to_bf16, gEl, b256, 0, stream, Wp[br], w_bf, n4M);
        gemm(stream, x_bf, w_bf, t0, NROWS, MD, MD, 0, 0, 0, 1, 0);
        hipLaunchKernelGGL(k_dwconv, gEl, b256, 0, stream, t0, dwp[br], qc_bf);
        hipLaunchKernelGGL(k_f32_to_bf16, gEl, b256, 0, stream, pwp[br], w_bf, n4M);
        gemm(stream, qc_bf, w_bf, t1, NROWS, MD, MD, 0, 0, 0, 1, 0);
        if (br == 0)      hipLaunchKernelGGL(k_silu_l2n, dim3(NROWS), b256, 0, stream, t1, q_bf);
        else if (br == 1) hipLaunchKernelGGL(k_silu_l2n, dim3(NROWS), b256, 0, stream, t1, k_bf);
        else              hipLaunchKernelGGL(k_silu_f32, gEl, b256, 0, stream, t1, vf, n4M);
    }

    // -- pred = k @ mem_state  (mem^T for NT)
    hipLaunchKernelGGL(transpose_to_bf16<float>, gT, bT, 0, stream, mem, w_bf, MD, MD, MD, 0);
    gemm(stream, k_bf, w_bf, t0, NROWS, MD, MD, 0, 0, 0, 1, 0);
    // err = v - pred; err^T; k^T
    hipLaunchKernelGGL(k_sub, gEl, b256, 0, stream, vf, t0, t1, n4M);
    hipLaunchKernelGGL(transpose_to_bf16<float>, gT, bT, 0, stream, t1, eT_bf, NROWS, MD, NROWS, 0);
    hipLaunchKernelGGL(transpose_to_bf16<unsigned short>, gT, bT, 0, stream, k_bf, kT_bf, NROWS, MD, NROWS, 0);
    // momentary*(B*L) = kT @ errT^T
    gemm(stream, kT_bf, eT_bf, t0, MD, MD, NROWS, 0, 0, 0, 1, 0);
    // snapshot
    hipLaunchKernelGGL(k_snap, gEl, b256, 0, stream, t0, mem, sur, scal, n4M);
    hipLaunchKernelGGL(transpose_to_bf16<float>, gT, bT, 0, stream, t0, sT_bf, MD, MD, MD, 0);
    // linear_ret = q @ snapshot
    gemm(stream, q_bf, sT_bf, ret, NROWS, MD, MD, 0, 0, 0, 1, 0);
    // mlp_ret = silu(q @ w1^T) @ w2^T   (accumulate into ret)
    hipLaunchKernelGGL(k_f32_to_bf16, gEl, b256, 0, stream, mw1, w_bf, n4M);
    gemm(stream, q_bf, w_bf, t0, NROWS, MD, MD, 0, 0, 0, 1, 0);
    hipLaunchKernelGGL(k_silu_bf16, gEl, b256, 0, stream, t0, qc_bf, n4M);
    hipLaunchKernelGGL(k_f32_to_bf16, gEl, b256, 0, stream, mw2, w_bf, n4M);
    gemm(stream, qc_bf, w_bf, ret, NROWS, MD, MD, 0, 0, 0, 1, 1);

    // -- attention: build k_wp [2][1152][M] and v_wp^T [2][M][1152]
    hipLaunchKernelGGL(k_pkn, dim3(8), b256, 0, stream, pk, kwp);
    hipLaunchKernelGGL(k_copy_k_kwp, gEl, b256, 0, stream, k_bf, kwp);
    hipLaunchKernelGGL(k_zero_kwp_tail, dim3(1920), b256, 0, stream, kwp);
    hipLaunchKernelGGL(k_pv_vwpT, dim3(64), b256, 0, stream, pv, vwpT);
    hipLaunchKernelGGL(transpose_to_bf16<float>, dim3(64, 32), bT, 0, stream,
                       vf, vwpT, 1024, MD, PLP, 8);
    hipLaunchKernelGGL(transpose_to_bf16<float>, dim3(64, 32), bT, 0, stream,
                       vf + (size_t)1024 * MD, vwpT + (size_t)MD * PLP, 1024, MD, PLP, 8);
    hipLaunchKernelGGL(k_zero_vwpT_tail, dim3(1920), b256, 0, stream, vwpT);
    // scores (both batches): S[b] = q[b] @ kwp[b]^T
    gemm(stream, q_bf, kwp, t0, 1024, PLP, MD,
         (long)1024 * MD, (long)PLP * MD, (long)1024 * PLP, 2, 0);
    hipLaunchKernelGGL(k_softmax, dim3(1024, 2), b256, 0, stream, t0, (unsigned short*)t1);
    // context: ret[b] += attn[b] @ vwpT[b]^T
    gemm(stream, (unsigned short*)t1, vwpT, ret, 1024, MD, PLP,
         (long)1024 * PLP, (long)MD * PLP, (long)1024 * MD, 2, 1);

    // -- gate + output projection + RMSNorm
    hipLaunchKernelGGL(k_f32_to_bf16, gEl, b256, 0, stream, ret, qc_bf, n4M);
    hipLaunchKernelGGL(k_f32_to_bf16, gEl, b256, 0, stream, gw, w_bf, n4M);
    gemm(stream, qc_bf, w_bf, t0, NROWS, MD, MD, 0, 0, 0, 1, 0);
    hipLaunchKernelGGL(k_gate, gEl, b256, 0, stream, t0, gb, ret, g_bf, n4M);
    hipLaunchKernelGGL(k_f32_to_bf16, gEl, b256, 0, stream, ow, w_bf, n4M);
    gemm(stream, g_bf, w_bf, t1, NROWS, MD, MD, 0, 0, 0, 1, 0);
    hipLaunchKernelGGL(k_final, dim3(NROWS), b256, 0, stream, x, t1, lnw, out);
}

// Round 2
// 1009.119 us; speedup vs baseline: 1.1189x; 1.1189x over previous
//
#include <hip/hip_runtime.h>
#include <hip/hip_bf16.h>

// ---------------------------------------------------------------------------
// TitansMemory: B=2, L=1024, D=M=2048, P=8, Kconv=4.
// All matmuls: bf16 NT-GEMM, 128x64 tile (grid 512 = 2 blocks/CU on the
// square GEMMs), global_load_lds width-16 staging with XOR-swizzled LDS
// layout, fused epilogues (bf16 store / silu-bf16 / accumulate).
// ---------------------------------------------------------------------------

#define NROWS 2048      // B*L
#define MD    2048      // D == M
#define PL    1032      // P + L
#define PLP   1152      // padded to multiple of 64

using bf16x8 = __attribute__((ext_vector_type(8))) __bf16;
using f32x4  = __attribute__((ext_vector_type(4))) float;

__device__ __forceinline__ unsigned short f2bf(float f) {
    union { float f; unsigned int u; } c; c.f = f;
    unsigned int u = c.u;
    return (unsigned short)((u + 0x7fffu + ((u >> 16) & 1u)) >> 16);
}
__device__ __forceinline__ float bf2f(unsigned short h) {
    union { float f; unsigned int u; } c; c.u = ((unsigned int)h) << 16;
    return c.f;
}
__device__ __forceinline__ float ldf(const float* p) { return *p; }
__device__ __forceinline__ float ldf(const unsigned short* p) { return bf2f(*p); }
__device__ __forceinline__ float sigm(float x) { return 1.f / (1.f + __expf(-x)); }
__device__ __forceinline__ float silu(float x) { return x / (1.f + __expf(-x)); }

__device__ __forceinline__ float block_reduce_sum(float v) {
    __shared__ float ws[4];
    #pragma unroll
    for (int o = 32; o > 0; o >>= 1) v += __shfl_down(v, o);
    __syncthreads();
    if ((threadIdx.x & 63) == 0) ws[threadIdx.x >> 6] = v;
    __syncthreads();
    return (ws[0] + ws[1]) + (ws[2] + ws[3]);
}
__device__ __forceinline__ float block_reduce_max(float v) {
    __shared__ float wm[4];
    #pragma unroll
    for (int o = 32; o > 0; o >>= 1) v = fmaxf(v, __shfl_down(v, o));
    __syncthreads();
    if ((threadIdx.x & 63) == 0) wm[threadIdx.x >> 6] = v;
    __syncthreads();
    return fmaxf(fmaxf(wm[0], wm[1]), fmaxf(wm[2], wm[3]));
}

__device__ __forceinline__ void load_lds16(const unsigned short* g, unsigned short* l) {
    __builtin_amdgcn_global_load_lds(
        (const __attribute__((address_space(1))) unsigned int*)g,
        (__attribute__((address_space(3))) unsigned int*)l, 16, 0, 0);
}

// ---------------- NT GEMM: C[n,m] = sum_k A[n,k]*B[m,k], bf16 in, fp32 acc.
// Tile 128(rows) x 64(cols), BK=64, 4 waves in 2x2, wave = 64x32 (4x2 frags).
// Staging: global_load_lds dwordx4; LDS chunk cl at row r holds global
// 16B-chunk cl ^ (r&7)  (conflict-free ds_read_b128 on the read side).
// epi: 0 = store f32, 1 = += f32, 2 = store bf16, 3 = silu -> bf16
__global__ __launch_bounds__(256) void gemm_nt(
    const unsigned short* __restrict__ A, const unsigned short* __restrict__ Bm,
    void* __restrict__ Cv, int N, int Mc, int K,
    long sA, long sB, long sC, int epi)
{
    __shared__ unsigned short As[128 * 64];
    __shared__ unsigned short Bs[64 * 64];
    const int tid = threadIdx.x, lane = tid & 63, w = tid >> 6;
    const int l16 = lane & 15, quad = lane >> 4;
    const int wr = (w >> 1) * 64, wc = (w & 1) * 32;
    const size_t rowBase = (size_t)blockIdx.y * 128;
    const size_t colBase = (size_t)blockIdx.x * 64;
    const unsigned short* Ap = A + (size_t)blockIdx.z * sA;
    const unsigned short* Bp = Bm + (size_t)blockIdx.z * sB;

    const int r8 = lane >> 3;            // row within 8-row chunk
    const int cg = (lane & 7) ^ r8;      // swizzled global 16B-chunk index

    const unsigned short* gA[4];
    const unsigned short* gB[2];
    unsigned short* lA[4];
    unsigned short* lB[2];
    #pragma unroll
    for (int t = 0; t < 4; ++t) {
        int ch = w * 4 + t;              // A chunks 0..15 (8 rows each)
        gA[t] = Ap + (rowBase + ch * 8 + r8) * (size_t)K + cg * 8;
        lA[t] = &As[ch * 512];
    }
    #pragma unroll
    for (int t = 0; t < 2; ++t) {
        int ch = w * 2 + t;              // B chunks 0..7
        gB[t] = Bp + (colBase + ch * 8 + r8) * (size_t)K + cg * 8;
        lB[t] = &Bs[ch * 512];
    }

    f32x4 acc[4][2] = {};

    for (int k0 = 0; k0 < K; k0 += 64) {
        #pragma unroll
        for (int t = 0; t < 4; ++t) { load_lds16(gA[t], lA[t]); gA[t] += 64; }
        #pragma unroll
        for (int t = 0; t < 2; ++t) { load_lds16(gB[t], lB[t]); gB[t] += 64; }
        __builtin_amdgcn_s_waitcnt(0);
        __syncthreads();
        #pragma unroll
        for (int ks = 0; ks < 2; ++ks) {
            const int cl = ((ks * 4 + quad) ^ (l16 & 7)) * 8;
            bf16x8 af[4], bfr[2];
            #pragma unroll
            for (int i = 0; i < 4; ++i)
                af[i] = *(const bf16x8*)&As[(wr + i * 16 + l16) * 64 + cl];
            #pragma unroll
            for (int j = 0; j < 2; ++j)
                bfr[j] = *(const bf16x8*)&Bs[(wc + j * 16 + l16) * 64 + cl];
            #pragma unroll
            for (int i = 0; i < 4; ++i)
                #pragma unroll
                for (int j = 0; j < 2; ++j)
                    acc[i][j] = __builtin_amdgcn_mfma_f32_16x16x32_bf16(af[i], bfr[j], acc[i][j], 0, 0, 0);
        }
        __syncthreads();
    }

    // C/D layout (verified round 0): col = lane&15, row = quad*4 + reg
    float* Cf = (float*)Cv + (size_t)blockIdx.z * sC;
    unsigned short* Ch = (unsigned short*)Cv + (size_t)blockIdx.z * sC;
    #pragma unroll
    for (int i = 0; i < 4; ++i)
        #pragma unroll
        for (int r = 0; r < 4; ++r) {
            size_t gr = rowBase + wr + i * 16 + quad * 4 + r;
            #pragma unroll
            for (int j = 0; j < 2; ++j) {
                size_t gc = colBase + wc + j * 16 + l16;
                size_t off = gr * (size_t)Mc + gc;
                float v = acc[i][j][r];
                if (epi == 0)      Cf[off] = v;
                else if (epi == 1) Cf[off] += v;
                else if (epi == 2) Ch[off] = f2bf(v);
                else               Ch[off] = f2bf(silu(v));
            }
        }
}

// ---------------- tiled transpose (+convert) to bf16, batched via z
// dst[z*sDst + c*dstLd + dstOff + r] = src[z*sSrc + r*C + c]
template <typename TS>
__global__ void k_transpose(const TS* __restrict__ src, unsigned short* __restrict__ dst,
                            int R, int C, int dstLd, int dstOff, long sSrc, long sDst)
{
    __shared__ float tile[32][33];
    const TS* sp = src + (size_t)blockIdx.z * sSrc;
    unsigned short* dp = dst + (size_t)blockIdx.z * sDst;
    int c0 = blockIdx.x * 32, r0 = blockIdx.y * 32;
    int tx = threadIdx.x, ty = threadIdx.y;     // 32 x 8
    #pragma unroll
    for (int i = 0; i < 4; ++i)
        tile[ty + i * 8][tx] = ldf(&sp[(size_t)(r0 + ty + i * 8) * C + c0 + tx]);
    __syncthreads();
    #pragma unroll
    for (int i = 0; i < 4; ++i)
        dp[(size_t)(c0 + ty + i * 8) * dstLd + dstOff + r0 + tx] = f2bf(tile[tx][ty + i * 8]);
}

// eT[m][n] = bf16( vf[n][m] - pred[n][m] )   (2048x2048)
__global__ void k_transpose_sub(const unsigned short* __restrict__ vf, const float* __restrict__ pred,
                                unsigned short* __restrict__ dst)
{
    __shared__ float tile[32][33];
    int c0 = blockIdx.x * 32, r0 = blockIdx.y * 32;
    int tx = threadIdx.x, ty = threadIdx.y;
    #pragma unroll
    for (int i = 0; i < 4; ++i) {
        size_t idx = (size_t)(r0 + ty + i * 8) * MD + c0 + tx;
        tile[ty + i * 8][tx] = bf2f(vf[idx]) - pred[idx];
    }
    __syncthreads();
    #pragma unroll
    for (int i = 0; i < 4; ++i)
        dst[(size_t)(c0 + ty + i * 8) * MD + r0 + tx] = f2bf(tile[tx][ty + i * 8]);
}

// snapT[h][d] = bf16( (1-a)*mem[d][h] + eta*sur[d][h] + (theta/2048)*momT[h][d] )
__global__ void k_snapT(const float* __restrict__ mem, const float* __restrict__ sur,
                        const float* __restrict__ momT, const float* __restrict__ scal,
                        unsigned short* __restrict__ dst)
{
    __shared__ float tile[32][33];
    float eta = scal[0], theta = scal[1], alpha = scal[2];
    int h0 = blockIdx.y * 32, d0 = blockIdx.x * 32;
    int tx = threadIdx.x, ty = threadIdx.y;
    #pragma unroll
    for (int i = 0; i < 4; ++i) {
        size_t idx = (size_t)(d0 + ty + i * 8) * MD + h0 + tx;
        tile[ty + i * 8][tx] = (1.f - alpha) * mem[idx] + eta * sur[idx];
    }
    __syncthreads();
    #pragma unroll
    for (int i = 0; i < 4; ++i) {
        size_t oidx = (size_t)(h0 + ty + i * 8) * MD + d0 + tx;
        dst[oidx] = f2bf(tile[tx][ty + i * 8] + theta * (1.f / 2048.f) * momT[oidx]);
    }
}

// ---------------- elementwise / small kernels ----------------
__global__ void k_f32_to_bf16(const float* __restrict__ in, unsigned short* __restrict__ o, int n) {
    int i = blockIdx.x * 256 + threadIdx.x;
    if (i < n) o[i] = f2bf(in[i]);
}
__global__ void k_cvt2(const float* __restrict__ s0, unsigned short* __restrict__ d0,
                       const float* __restrict__ s1, unsigned short* __restrict__ d1, int n) {
    int i = blockIdx.x * 256 + threadIdx.x;
    if (i < n) d0[i] = f2bf(s0[i]);
    else if (i - n < n) d1[i - n] = f2bf(s1[i - n]);
}
__global__ void k_silu_bf16(const float* __restrict__ in, unsigned short* __restrict__ o, int n) {
    int i = blockIdx.x * 256 + threadIdx.x;
    if (i < n) o[i] = f2bf(silu(in[i]));
}
__global__ void k_gate(const float* __restrict__ pre, const float* __restrict__ gb,
                       const float* __restrict__ ret, unsigned short* __restrict__ o, int n) {
    int i = blockIdx.x * 256 + threadIdx.x;
    if (i < n) {
        int m = i & (MD - 1);
        o[i] = f2bf(sigm(pre[i] + gb[m]) * ret[i]);
    }
}
// depthwise causal conv (K=4), bf16 in, bf16 out. xin: [B*L, M]
__global__ void k_dwconv(const unsigned short* __restrict__ xin, const float* __restrict__ dw,
                         unsigned short* __restrict__ o) {
    long i = (long)blockIdx.x * 256 + threadIdx.x;
    int m = (int)(i & (MD - 1));
    long n = i >> 11;
    int l = (int)(n & 1023);
    float s = 0.f;
    #pragma unroll
    for (int j = 0; j < 4; ++j) {
        int dl = j - 3;
        if (l + dl >= 0) s += dw[m * 4 + j] * bf2f(xin[i + (long)dl * MD]);
    }
    o[i] = f2bf(s);
}
__global__ void k_silu_l2n(const float* __restrict__ in, unsigned short* __restrict__ o) {
    int n = blockIdx.x;
    const float* row = in + (size_t)n * MD;
    int t = threadIdx.x;
    float v[8]; float ss = 0.f;
    #pragma unroll
    for (int s = 0; s < 8; ++s) { float y = silu(row[t + s * 256]); v[s] = y; ss += y * y; }
    ss = block_reduce_sum(ss);
    float inv = 1.f / (sqrtf(ss) + 1e-6f);
    #pragma unroll
    for (int s = 0; s < 8; ++s) o[(size_t)n * MD + t + s * 256] = f2bf(v[s] * inv);
}
__global__ void k_pooled(const float* __restrict__ x, const float* __restrict__ ew,
                         const float* __restrict__ tw, const float* __restrict__ aw,
                         float* __restrict__ dots) {
    int b = blockIdx.y;
    size_t base = (size_t)b * 1024 * MD;
    size_t start = (size_t)blockIdx.x * 8192;
    float s0 = 0, s1 = 0, s2 = 0;
    for (int s = 0; s < 32; ++s) {
        size_t f = start + threadIdx.x + (size_t)s * 256;
        float xv = x[base + f];
        int d = (int)(f & (MD - 1));
        s0 += xv * ew[d]; s1 += xv * tw[d]; s2 += xv * aw[d];
    }
    s0 = block_reduce_sum(s0);
    if (threadIdx.x == 0) atomicAdd(&dots[0 + b], s0);
    s1 = block_reduce_sum(s1);
    if (threadIdx.x == 0) atomicAdd(&dots[2 + b], s1);
    s2 = block_reduce_sum(s2);
    if (threadIdx.x == 0) atomicAdd(&dots[4 + b], s2);
}
__global__ void k_scal_fin(const float* __restrict__ dots, const float* __restrict__ eb,
                           const float* __restrict__ tb, const float* __restrict__ ab,
                           float* __restrict__ scal) {
    if (threadIdx.x == 0 && blockIdx.x == 0) {
        const float invL = 1.f / 1024.f;
        float e = 0, th = 0, al = 0;
        for (int b = 0; b < 2; ++b) {
            e  += sigm(dots[0 + b] * invL + eb[0]);
            th += sigm(dots[2 + b] * invL + tb[0]);
            al += sigm(dots[4 + b] * invL + ab[0]);
        }
        scal[0] = e * 0.5f; scal[1] = th * 0.5f; scal[2] = al * 0.5f;
    }
}
__global__ void k_pkn(const float* __restrict__ pk, unsigned short* __restrict__ kwp) {
    int p = blockIdx.x;
    int t = threadIdx.x;
    float v[8]; float ss = 0.f;
    #pragma unroll
    for (int s = 0; s < 8; ++s) { float y = pk[p * MD + t + s * 256]; v[s] = y; ss += y * y; }
    ss = block_reduce_sum(ss);
    float inv = 1.f / (sqrtf(ss) + 1e-6f);
    #pragma unroll
    for (int s = 0; s < 8; ++s) {
        unsigned short h = f2bf(v[s] * inv);
        kwp[(size_t)p * MD + t + s * 256] = h;
        kwp[(size_t)PLP * MD + (size_t)p * MD + t + s * 256] = h;
    }
}
__global__ void k_copy_k_kwp(const unsigned short* __restrict__ kb, unsigned short* __restrict__ kwp) {
    long i = (long)blockIdx.x * 256 + threadIdx.x;
    int m = (int)(i & (MD - 1));
    long n = i >> 11;
    int l = (int)(n & 1023); int b = (int)(n >> 10);
    kwp[((size_t)b * PLP + 8 + l) * MD + m] = kb[i];
}
__global__ void k_zero_kwp_tail(unsigned short* __restrict__ kwp) {
    long i = (long)blockIdx.x * 256 + threadIdx.x;
    int m = (int)(i & (MD - 1));
    long r = i >> 11;
    int j = PL + (int)(r % 120); int b = (int)(r / 120);
    kwp[((size_t)b * PLP + j) * MD + m] = 0;
}
__global__ void k_pv_vwpT(const float* __restrict__ pv, unsigned short* __restrict__ vwpT) {
    long i = (long)blockIdx.x * 256 + threadIdx.x;
    int pp = (int)(i & 7); int m = (int)(i >> 3);
    unsigned short h = f2bf(pv[pp * MD + m]);
    vwpT[(size_t)m * PLP + pp] = h;
    vwpT[(size_t)MD * PLP + (size_t)m * PLP + pp] = h;
}
__global__ void k_zero_vwpT_tail(unsigned short* __restrict__ vwpT) {
    long i = (long)blockIdx.x * 256 + threadIdx.x;
    int pp = PL + (int)(i % 120);
    long bm = i / 120;
    vwpT[(size_t)bm * PLP + pp] = 0;
}
__global__ void k_softmax(const float* __restrict__ S, unsigned short* __restrict__ attn) {
    int l = blockIdx.x, b = blockIdx.y;
    size_t base = ((size_t)b * 1024 + l) * PLP;
    int nvis = 8 + l + 1;
    const float scale = 0.022097086912079608f;  // 1/sqrt(2048)
    int t = threadIdx.x;
    float vals[5];
    float mx = -1e30f;
    #pragma unroll
    for (int s = 0; s < 5; ++s) {
        int j = t + s * 256;
        float v = -1e30f;
        if (j < nvis) v = S[base + j] * scale;
        vals[s] = v;
        mx = fmaxf(mx, v);
    }
    mx = block_reduce_max(mx);
    float sum = 0.f;
    #pragma unroll
    for (int s = 0; s < 5; ++s) {
        int j = t + s * 256;
        float e = 0.f;
        if (j < nvis) e = __expf(vals[s] - mx);
        vals[s] = e; sum += e;
    }
    sum = block_reduce_sum(sum);
    float inv = 1.f / sum;
    #pragma unroll
    for (int s = 0; s < 5; ++s) {
        int j = t + s * 256;
        if (j < PLP) attn[base + j] = f2bf(vals[s] * inv);
    }
}
__global__ void k_final(const float* __restrict__ x, const float* __restrict__ y,
                        const float* __restrict__ lnw, float* __restrict__ out) {
    int n = blockIdx.x;
    size_t base = (size_t)n * MD;
    int t = threadIdx.x;
    float v[8]; float ss = 0.f;
    #pragma unroll
    for (int s = 0; s < 8; ++s) {
        float o = x[base + t + s * 256] + y[base + t + s * 256];
        v[s] = o; ss += o * o;
    }
    ss = block_reduce_sum(ss);
    float inv = rsqrtf(ss * (1.f / 2048.f) + 1e-6f);
    #pragma unroll
    for (int s = 0; s < 8; ++s)
        out[base + t + s * 256] = v[s] * inv * lnw[t + s * 256];
}

// ---------------- host-side launch helper ----------------
static inline void gemm(hipStream_t st, const void* A, const void* B, void* C,
                        int N, int Mc, int K, long sA, long sB, long sC, int z, int epi) {
    dim3 g(Mc / 64, N / 128, z);
    hipLaunchKernelGGL(gemm_nt, g, dim3(256), 0, st,
                       (const unsigned short*)A, (const unsigned short*)B, C,
                       N, Mc, K, sA, sB, sC, epi);
}

extern "C" void kernel_launch(void* const* d_in, const int* in_sizes, int n_in,
                              void* d_out, int out_size, void* d_ws, size_t ws_size,
                              hipStream_t stream) {
    const float* x    = (const float*)d_in[0];
    const float* Wq   = (const float*)d_in[1];
    const float* Wk   = (const float*)d_in[2];
    const float* Wv   = (const float*)d_in[3];
    const float* qdw  = (const float*)d_in[4];
    const float* kdw  = (const float*)d_in[5];
    const float* vdw  = (const float*)d_in[6];
    const float* qpw  = (const float*)d_in[7];
    const float* kpw  = (const float*)d_in[8];
    const float* vpw  = (const float*)d_in[9];
    const float* pk   = (const float*)d_in[10];
    const float* pv   = (const float*)d_in[11];
    const float* mw1  = (const float*)d_in[12];
    const float* mw2  = (const float*)d_in[13];
    const float* etaw = (const float*)d_in[14];
    const float* etab = (const float*)d_in[15];
    const float* thw  = (const float*)d_in[16];
    const float* thb  = (const float*)d_in[17];
    const float* alw  = (const float*)d_in[18];
    const float* alb  = (const float*)d_in[19];
    const float* gw   = (const float*)d_in[20];
    const float* gb   = (const float*)d_in[21];
    const float* ow   = (const float*)d_in[22];
    const float* lnw  = (const float*)d_in[23];
    const float* mem  = (const float*)d_in[24];
    const float* sur  = (const float*)d_in[25];
    float* out = (float*)d_out;

    char* ws = (char*)d_ws;
    float* dots = (float*)ws;            // 6 floats
    float* scal = (float*)(ws + 1024);   // 3 floats
    size_t cur = 4096;
    auto take = [&](size_t bytes) -> char* {
        char* p = ws + cur; cur += (bytes + 255) & ~(size_t)255; return p;
    };
    const size_t NM = (size_t)NROWS * MD;           // 4,194,304
    float* t0  = (float*)take(NM * 4);              // fp32 scratch (GEMM outs)
    float* ret = (float*)take(NM * 4);
    unsigned short* x_bf  = (unsigned short*)take(NM * 2);
    unsigned short* wA    = (unsigned short*)take(NM * 2);   // weight slot A
    unsigned short* wB    = (unsigned short*)take(NM * 2);   // weight slot B
    unsigned short* tproj = (unsigned short*)take(NM * 2);   // proj out (per branch)
    unsigned short* conv  = (unsigned short*)take(NM * 2);   // dwconv out (per branch)
    unsigned short* q_bf  = (unsigned short*)take(NM * 2);
    unsigned short* k_bf  = (unsigned short*)take(NM * 2);
    unsigned short* vf    = (unsigned short*)take(NM * 2);   // silu(v) bf16
    unsigned short* kT    = (unsigned short*)take(NM * 2);
    unsigned short* eT    = (unsigned short*)take(NM * 2);   // errT; later attn
    unsigned short* qc    = (unsigned short*)take(NM * 2);   // silu(mlp1); later ret bf16
    unsigned short* g_bf  = (unsigned short*)take(NM * 2);
    unsigned short* kwp   = (unsigned short*)take((size_t)2 * PLP * MD * 2);
    unsigned short* vwpT  = (unsigned short*)take((size_t)2 * MD * PLP * 2);
    unsigned short* attn  = eT;                               // reuse (after momT)

    const int n4M = (int)NM;
    const dim3 b256(256);
    const dim3 gEl(n4M / 256);
    const dim3 bT(32, 8);

    // -- scalars eta/theta/alpha
    hipMemsetAsync(dots, 0, 256, stream);
    hipLaunchKernelGGL(k_pooled, dim3(256, 2), b256, 0, stream, x, etaw, thw, alw, dots);
    hipLaunchKernelGGL(k_scal_fin, dim3(1), dim3(64), 0, stream, dots, etab, thb, alb, scal);

    // -- x to bf16
    hipLaunchKernelGGL(k_f32_to_bf16, gEl, b256, 0, stream, x, x_bf, n4M);

    // -- q / k / v branches
    const float* Wp[3]  = {Wq, Wk, Wv};
    const float* dwp[3] = {qdw, kdw, vdw};
    const float* pwp[3] = {qpw, kpw, vpw};
    for (int br = 0; br < 3; ++br) {
        hipLaunchKernelGGL(k_cvt2, dim3(2 * n4M / 256), b256, 0, stream,
                           Wp[br], wA, pwp[br], wB, n4M);
        gemm(stream, x_bf, wA, tproj, NROWS, MD, MD, 0, 0, 0, 1, 2);   // bf16 out
        hipLaunchKernelGGL(k_dwconv, gEl, b256, 0, stream, tproj, dwp[br], conv);
        if (br == 2) {
            gemm(stream, conv, wB, vf, NROWS, MD, MD, 0, 0, 0, 1, 3);  // silu->bf16
        } else {
            gemm(stream, conv, wB, t0, NROWS, MD, MD, 0, 0, 0, 1, 0);  // f32
            hipLaunchKernelGGL(k_silu_l2n, dim3(NROWS), b256, 0, stream, t0,
                               br == 0 ? q_bf : k_bf);
        }
    }

    // -- pred = k @ mem^T-rows  (memT into wA)
    hipLaunchKernelGGL(k_transpose<float>, dim3(64, 64, 1), bT, 0, stream,
                       mem, wA, MD, MD, MD, 0, 0L, 0L);
    gemm(stream, k_bf, wA, t0, NROWS, MD, MD, 0, 0, 0, 1, 0);
    // errT, kT
    hipLaunchKernelGGL(k_transpose_sub, dim3(64, 64), bT, 0, stream, vf, t0, eT);
    hipLaunchKernelGGL(k_transpose<unsigned short>, dim3(64, 64, 1), bT, 0, stream,
                       k_bf, kT, NROWS, MD, MD, 0, 0L, 0L);
    // momT = errT . kT (NT)  -> t0
    gemm(stream, eT, kT, t0, MD, MD, NROWS, 0, 0, 0, 1, 0);
    // snapT -> wA
    hipLaunchKernelGGL(k_snapT, dim3(64, 64), bT, 0, stream, mem, sur, t0, scal, wA);
    // linear_ret = q . snapT (NT) -> ret
    gemm(stream, q_bf, wA, ret, NROWS, MD, MD, 0, 0, 0, 1, 0);
    // mlp: silu(q @ w1^T) @ w2^T  += ret
    hipLaunchKernelGGL(k_f32_to_bf16, gEl, b256, 0, stream, mw1, wB, n4M);
    gemm(stream, q_bf, wB, t0, NROWS, MD, MD, 0, 0, 0, 1, 0);
    hipLaunchKernelGGL(k_silu_bf16, gEl, b256, 0, stream, t0, qc, n4M);
    hipLaunchKernelGGL(k_f32_to_bf16, gEl, b256, 0, stream, mw2, wB, n4M);
    gemm(stream, qc, wB, ret, NROWS, MD, MD, 0, 0, 0, 1, 1);

    // -- attention
    hipLaunchKernelGGL(k_pkn, dim3(8), b256, 0, stream, pk, kwp);
    hipLaunchKernelGGL(k_copy_k_kwp, gEl, b256, 0, stream, k_bf, kwp);
    hipLaunchKernelGGL(k_zero_kwp_tail, dim3(1920), b256, 0, stream, kwp);
    hipLaunchKernelGGL(k_pv_vwpT, dim3(64), b256, 0, stream, pv, vwpT);
    hipLaunchKernelGGL(k_transpose<unsigned short>, dim3(64, 32, 2), bT, 0, stream,
                       vf, vwpT, 1024, MD, PLP, 8, (long)1024 * MD, (long)MD * PLP);
    hipLaunchKernelGGL(k_zero_vwpT_tail, dim3(1920), b256, 0, stream, vwpT);
    gemm(stream, q_bf, kwp, t0, 1024, PLP, MD,
         (long)1024 * MD, (long)PLP * MD, (long)1024 * PLP, 2, 0);
    hipLaunchKernelGGL(k_softmax, dim3(1024, 2), b256, 0, stream, t0, attn);
    gemm(stream, attn, vwpT, ret, 1024, MD, PLP,
         (long)1024 * PLP, (long)MD * PLP, (long)1024 * MD, 2, 1);

    // -- gate + output projection + RMSNorm
    hipLaunchKernelGGL(k_cvt2, dim3(2 * n4M / 256), b256, 0, stream, gw, wA, ow, wB, n4M);
    hipLaunchKernelGGL(k_f32_to_bf16, gEl, b256, 0, stream, ret, qc, n4M);
    gemm(stream, qc, wA, t0, NROWS, MD, MD, 0, 0, 0, 1, 0);
    hipLaunchKernelGGL(k_gate, gEl, b256, 0, stream, t0, gb, ret, g_bf, n4M);
    gemm(stream, g_bf, wB, t0, NROWS, MD, MD, 0, 0, 0, 1, 0);
    hipLaunchKernelGGL(k_final, dim3(NROWS), b256, 0, stream, x, t0, lnw, out);
}

// Round 3
// 801.813 us; speedup vs baseline: 1.4081x; 1.2585x over previous
//
#include <hip/hip_runtime.h>
#include <hip/hip_bf16.h>

// ---------------------------------------------------------------------------
// TitansMemory: B=2, L=1024, D=M=2048, P=8, Kconv=4.
// bf16 NT-GEMM, 128x64 tile, DOUBLE-BUFFERED global_load_lds (raw s_barrier +
// vmcnt(6) prefetch), XOR-swizzled LDS. Batched GEMMs: wide qkv-proj (M=6144),
// z3 pointwise conv, z2 {pred,mlp1}, z2 {linret,mlp2}. Fused/vectorized
// elementwise passes.
// ---------------------------------------------------------------------------

#define NROWS 2048      // B*L
#define MD    2048      // D == M
#define PL    1032      // P + L
#define PLP   1152      // padded
#define NM    4194304   // 2048*2048

using bf16x8 = __attribute__((ext_vector_type(8))) __bf16;
using f32x4  = __attribute__((ext_vector_type(4))) float;
using u16x8  = __attribute__((ext_vector_type(8))) unsigned short;

__device__ __forceinline__ unsigned short f2bf(float f) {
    union { float f; unsigned int u; } c; c.f = f;
    unsigned int u = c.u;
    return (unsigned short)((u + 0x7fffu + ((u >> 16) & 1u)) >> 16);
}
__device__ __forceinline__ float bf2f(unsigned short h) {
    union { float f; unsigned int u; } c; c.u = ((unsigned int)h) << 16;
    return c.f;
}
__device__ __forceinline__ float ldf(const float* p) { return *p; }
__device__ __forceinline__ float ldf(const unsigned short* p) { return bf2f(*p); }
__device__ __forceinline__ float sigm(float x) { return 1.f / (1.f + __expf(-x)); }
__device__ __forceinline__ float silu(float x) { return x / (1.f + __expf(-x)); }

__device__ __forceinline__ float block_reduce_sum(float v) {
    __shared__ float ws[4];
    #pragma unroll
    for (int o = 32; o > 0; o >>= 1) v += __shfl_down(v, o);
    __syncthreads();
    if ((threadIdx.x & 63) == 0) ws[threadIdx.x >> 6] = v;
    __syncthreads();
    return (ws[0] + ws[1]) + (ws[2] + ws[3]);
}
__device__ __forceinline__ float block_reduce_max(float v) {
    __shared__ float wm[4];
    #pragma unroll
    for (int o = 32; o > 0; o >>= 1) v = fmaxf(v, __shfl_down(v, o));
    __syncthreads();
    if ((threadIdx.x & 63) == 0) wm[threadIdx.x >> 6] = v;
    __syncthreads();
    return fmaxf(fmaxf(wm[0], wm[1]), fmaxf(wm[2], wm[3]));
}

__device__ __forceinline__ void load_lds16(const unsigned short* g, unsigned short* l) {
    __builtin_amdgcn_global_load_lds(
        (const __attribute__((address_space(1))) unsigned int*)g,
        (__attribute__((address_space(3))) unsigned int*)l, 16, 0, 0);
}
__device__ __forceinline__ void raw_barrier() {
    __asm__ volatile("" ::: "memory");
    __builtin_amdgcn_s_barrier();
    __asm__ volatile("" ::: "memory");
}

// ---------------- NT GEMM: C[n,m] = sum_k A[n,k]*B[m,k], bf16 in, fp32 acc.
// 128x64 tile, BK=64, double-buffered LDS. epi: 0=f32, 1=+=f32, 2=bf16, 3=silu->bf16
__global__ __launch_bounds__(256) void gemm_nt(
    const unsigned short* __restrict__ A, const unsigned short* __restrict__ Bm,
    void* __restrict__ Cv, int Mc, int K, long sA, long sB, long sC, int epi)
{
    __shared__ unsigned short As[2][8192];
    __shared__ unsigned short Bs[2][4096];
    const int tid = threadIdx.x, lane = tid & 63, w = tid >> 6;
    const int l16 = lane & 15, quad = lane >> 4;
    const int wr = (w >> 1) * 64, wc = (w & 1) * 32;
    const long rowBase = (long)blockIdx.y * 128;
    const long colBase = (long)blockIdx.x * 64;
    const unsigned short* Ap = A + (long)blockIdx.z * sA;
    const unsigned short* Bp = Bm + (long)blockIdx.z * sB;
    const int r8 = lane >> 3;
    const int cg = (lane & 7) ^ r8;          // swizzled global 16B-chunk

    const unsigned short* gA[4]; const unsigned short* gB[2];
    unsigned short* lA[4]; unsigned short* lB[2];
    #pragma unroll
    for (int t = 0; t < 4; ++t) {
        int ch = w * 4 + t;
        gA[t] = Ap + (rowBase + ch * 8 + r8) * (long)K + cg * 8;
        lA[t] = &As[0][ch * 512];
    }
    #pragma unroll
    for (int t = 0; t < 2; ++t) {
        int ch = w * 2 + t;
        gB[t] = Bp + (colBase + ch * 8 + r8) * (long)K + cg * 8;
        lB[t] = &Bs[0][ch * 512];
    }

    f32x4 acc[4][2] = {};
    // prologue: stage tile 0 into buffer 0
    #pragma unroll
    for (int t = 0; t < 4; ++t) { load_lds16(gA[t], lA[t]); gA[t] += 64; }
    #pragma unroll
    for (int t = 0; t < 2; ++t) { load_lds16(gB[t], lB[t]); gB[t] += 64; }

    const int nIter = K >> 6;
    for (int it = 0; it < nIter; ++it) {
        const int cb = it & 1;
        if (it + 1 < nIter) {
            const int nb = cb ^ 1;
            #pragma unroll
            for (int t = 0; t < 4; ++t) { load_lds16(gA[t], lA[t] + nb * 8192); gA[t] += 64; }
            #pragma unroll
            for (int t = 0; t < 2; ++t) { load_lds16(gB[t], lB[t] + nb * 4096); gB[t] += 64; }
            __builtin_amdgcn_s_waitcnt(0xF76);   // vmcnt<=6: tile `it` landed, next in flight
        } else {
            __builtin_amdgcn_s_waitcnt(0xF70);   // vmcnt(0)
        }
        raw_barrier();
        const unsigned short* Ac = As[cb];
        const unsigned short* Bc = Bs[cb];
        #pragma unroll
        for (int ks = 0; ks < 2; ++ks) {
            const int cl = ((ks * 4 + quad) ^ (l16 & 7)) * 8;
            bf16x8 af[4], bfr[2];
            #pragma unroll
            for (int i = 0; i < 4; ++i)
                af[i] = *(const bf16x8*)&Ac[(wr + i * 16 + l16) * 64 + cl];
            #pragma unroll
            for (int j = 0; j < 2; ++j)
                bfr[j] = *(const bf16x8*)&Bc[(wc + j * 16 + l16) * 64 + cl];
            #pragma unroll
            for (int i = 0; i < 4; ++i)
                #pragma unroll
                for (int j = 0; j < 2; ++j)
                    acc[i][j] = __builtin_amdgcn_mfma_f32_16x16x32_bf16(af[i], bfr[j], acc[i][j], 0, 0, 0);
        }
        raw_barrier();
    }

    // C/D layout: col = lane&15, row = quad*4 + reg
    float* Cf = (float*)Cv + (long)blockIdx.z * sC;
    unsigned short* Ch = (unsigned short*)Cv + (long)blockIdx.z * sC;
    #pragma unroll
    for (int i = 0; i < 4; ++i)
        #pragma unroll
        for (int r = 0; r < 4; ++r) {
            long gr = rowBase + wr + i * 16 + quad * 4 + r;
            #pragma unroll
            for (int j = 0; j < 2; ++j) {
                long gc = colBase + wc + j * 16 + l16;
                long off = gr * (long)Mc + gc;
                float v = acc[i][j][r];
                if (epi == 0)      Cf[off] = v;
                else if (epi == 1) Cf[off] += v;
                else if (epi == 2) Ch[off] = f2bf(v);
                else               Ch[off] = f2bf(silu(v));
            }
        }
}

// ---------------- tiled transpose (+convert) to bf16, batched via z
template <typename TS>
__global__ void k_transpose(const TS* __restrict__ src, unsigned short* __restrict__ dst,
                            int R, int C, int dstLd, int dstOff, long sSrc, long sDst)
{
    __shared__ float tile[32][33];
    const TS* sp = src + (long)blockIdx.z * sSrc;
    unsigned short* dp = dst + (long)blockIdx.z * sDst;
    int c0 = blockIdx.x * 32, r0 = blockIdx.y * 32;
    int tx = threadIdx.x, ty = threadIdx.y;     // 32 x 8
    #pragma unroll
    for (int i = 0; i < 4; ++i)
        tile[ty + i * 8][tx] = ldf(&sp[(long)(r0 + ty + i * 8) * C + c0 + tx]);
    __syncthreads();
    #pragma unroll
    for (int i = 0; i < 4; ++i)
        dp[(long)(c0 + ty + i * 8) * dstLd + dstOff + r0 + tx] = f2bf(tile[tx][ty + i * 8]);
}

// z0: eT[m][n] = bf16(vf[n][m]-pred[n][m]); z1: kT[m][n] = k_bf[n][m]
__global__ void k_errT_kT(const unsigned short* __restrict__ vf, const float* __restrict__ pred,
                          const unsigned short* __restrict__ k_bf, unsigned short* __restrict__ eT)
{
    __shared__ float tile[32][33];
    int z = blockIdx.z;
    int c0 = blockIdx.x * 32, r0 = blockIdx.y * 32;
    int tx = threadIdx.x, ty = threadIdx.y;
    #pragma unroll
    for (int i = 0; i < 4; ++i) {
        long idx = (long)(r0 + ty + i * 8) * MD + c0 + tx;
        tile[ty + i * 8][tx] = (z == 0) ? (bf2f(vf[idx]) - pred[idx]) : bf2f(k_bf[idx]);
    }
    __syncthreads();
    unsigned short* dst = eT + (long)z * NM;
    #pragma unroll
    for (int i = 0; i < 4; ++i)
        dst[(long)(c0 + ty + i * 8) * MD + r0 + tx] = f2bf(tile[tx][ty + i * 8]);
}

// snapT[h][d] = bf16((1-a)*mem[d][h] + eta*sur[d][h] + (theta/2048)*momT[h][d])
__global__ void k_snapT(const float* __restrict__ mem, const float* __restrict__ sur,
                        const float* __restrict__ momT, const float* __restrict__ scal,
                        unsigned short* __restrict__ dst)
{
    __shared__ float tile[32][33];
    float eta = scal[0], theta = scal[1], alpha = scal[2];
    int h0 = blockIdx.y * 32, d0 = blockIdx.x * 32;
    int tx = threadIdx.x, ty = threadIdx.y;
    #pragma unroll
    for (int i = 0; i < 4; ++i) {
        long idx = (long)(d0 + ty + i * 8) * MD + h0 + tx;
        tile[ty + i * 8][tx] = (1.f - alpha) * mem[idx] + eta * sur[idx];
    }
    __syncthreads();
    #pragma unroll
    for (int i = 0; i < 4; ++i) {
        long oidx = (long)(h0 + ty + i * 8) * MD + d0 + tx;
        dst[oidx] = f2bf(tile[tx][ty + i * 8] + theta * (1.f / 2048.f) * momT[oidx]);
    }
}

// ---------------- fused / vectorized elementwise ----------------
// 8-segment fp32->bf16 convert; 2048 blocks per 4M-element segment
__global__ void k_cvt_multi(const float* s0, const float* s1, const float* s2, const float* s3,
                            const float* s4, const float* s5, const float* s6, const float* s7,
                            unsigned short* d0, unsigned short* d1, unsigned short* d2, unsigned short* d3,
                            unsigned short* d4, unsigned short* d5, unsigned short* d6, unsigned short* d7)
{
    int seg = blockIdx.x >> 11;
    const float* s; unsigned short* d;
    switch (seg) {
        case 0: s = s0; d = d0; break;  case 1: s = s1; d = d1; break;
        case 2: s = s2; d = d2; break;  case 3: s = s3; d = d3; break;
        case 4: s = s4; d = d4; break;  case 5: s = s5; d = d5; break;
        case 6: s = s6; d = d6; break;  default: s = s7; d = d7; break;
    }
    long idx = ((long)(blockIdx.x & 2047) * 256 + threadIdx.x) * 8;
    float4 a = *(const float4*)(s + idx);
    float4 b = *(const float4*)(s + idx + 4);
    u16x8 o;
    o[0] = f2bf(a.x); o[1] = f2bf(a.y); o[2] = f2bf(a.z); o[3] = f2bf(a.w);
    o[4] = f2bf(b.x); o[5] = f2bf(b.y); o[6] = f2bf(b.z); o[7] = f2bf(b.w);
    *(u16x8*)(d + idx) = o;
}

// depthwise causal conv z3, vec8. tproj: [2048][6144] bf16; conv: [3][2048][2048]
__global__ void k_dwconv(const unsigned short* __restrict__ tproj,
                         const float* __restrict__ qdw, const float* __restrict__ kdw,
                         const float* __restrict__ vdw, unsigned short* __restrict__ conv)
{
    long u = (long)blockIdx.x * 256 + threadIdx.x;
    long flat = u * 8;
    int z = (int)(flat >> 22);
    int rem = (int)(flat & (NM - 1));
    int n = rem >> 11, m = rem & 2047;
    int l = n & 1023;
    const float* dw = (z == 0) ? qdw : (z == 1) ? kdw : vdw;
    const unsigned short* src = tproj + (long)n * 6144 + z * 2048 + m;
    float4 dwv[8];
    #pragma unroll
    for (int e = 0; e < 8; ++e) dwv[e] = *(const float4*)(dw + (m + e) * 4);
    float acc[8] = {};
    #pragma unroll
    for (int j = 0; j < 4; ++j) {
        int dl = j - 3;
        if (l + dl >= 0) {
            u16x8 r = *(const u16x8*)(src + (long)dl * 6144);
            #pragma unroll
            for (int e = 0; e < 8; ++e)
                acc[e] += ((const float*)&dwv[e])[j] * bf2f(r[e]);
        }
    }
    u16x8 o;
    #pragma unroll
    for (int e = 0; e < 8; ++e) o[e] = f2bf(acc[e]);
    *(u16x8*)(conv + (long)z * NM + (long)n * 2048 + m) = o;
}

// post-pointwise: z0/z1: silu+l2n -> q_bf / (k_bf + kwp); z2: silu -> vf
__global__ void k_post_qkv(const float* __restrict__ t_big, unsigned short* __restrict__ q_bf,
                           unsigned short* __restrict__ k_bf, unsigned short* __restrict__ vf,
                           unsigned short* __restrict__ kwp)
{
    int bid = blockIdx.x, z = bid >> 11, n = bid & 2047;
    const float* row = t_big + (long)z * NM + (long)n * 2048;
    int t = threadIdx.x;
    float4 a = *(const float4*)(row + t * 8);
    float4 b = *(const float4*)(row + t * 8 + 4);
    float v[8] = {silu(a.x), silu(a.y), silu(a.z), silu(a.w),
                  silu(b.x), silu(b.y), silu(b.z), silu(b.w)};
    if (z == 2) {
        u16x8 o;
        #pragma unroll
        for (int e = 0; e < 8; ++e) o[e] = f2bf(v[e]);
        *(u16x8*)(vf + (long)n * 2048 + t * 8) = o;
        return;
    }
    float ss = 0.f;
    #pragma unroll
    for (int e = 0; e < 8; ++e) ss += v[e] * v[e];
    ss = block_reduce_sum(ss);
    float inv = 1.f / (sqrtf(ss) + 1e-6f);
    u16x8 o;
    #pragma unroll
    for (int e = 0; e < 8; ++e) o[e] = f2bf(v[e] * inv);
    if (z == 0) {
        *(u16x8*)(q_bf + (long)n * 2048 + t * 8) = o;
    } else {
        *(u16x8*)(k_bf + (long)n * 2048 + t * 8) = o;
        int bb = n >> 10, l = n & 1023;
        *(u16x8*)(kwp + ((long)bb * PLP + 8 + l) * MD + t * 8) = o;
    }
}

// misc: pkn rows (8) | pv->vwpT (64) | kwp tail zero (240) | vwpT tail zero (240)
__global__ void k_misc(const float* __restrict__ pk, const float* __restrict__ pv,
                       unsigned short* __restrict__ kwp, unsigned short* __restrict__ vwpT)
{
    int bid = blockIdx.x, t = threadIdx.x;
    if (bid < 8) {
        const float* row = pk + bid * MD;
        float4 a = *(const float4*)(row + t * 8);
        float4 b = *(const float4*)(row + t * 8 + 4);
        float v[8] = {a.x, a.y, a.z, a.w, b.x, b.y, b.z, b.w};
        float ss = 0.f;
        #pragma unroll
        for (int e = 0; e < 8; ++e) ss += v[e] * v[e];
        ss = block_reduce_sum(ss);
        float inv = 1.f / (sqrtf(ss) + 1e-6f);
        u16x8 o;
        #pragma unroll
        for (int e = 0; e < 8; ++e) o[e] = f2bf(v[e] * inv);
        *(u16x8*)(kwp + (long)bid * MD + t * 8) = o;
        *(u16x8*)(kwp + (long)PLP * MD + (long)bid * MD + t * 8) = o;
    } else if (bid < 72) {
        int i = (bid - 8) * 256 + t;         // 16384 = 2048*8
        int m = i >> 3, pp = i & 7;
        unsigned short h = f2bf(pv[pp * MD + m]);
        vwpT[(long)m * PLP + pp] = h;
        vwpT[(long)MD * PLP + (long)m * PLP + pp] = h;
    } else if (bid < 312) {
        long flat = ((long)(bid - 72) * 256 + t) * 8;    // 2*120*2048
        int b = (int)(flat / 245760);
        int r = (int)(flat % 245760);
        int j = 1032 + (r >> 11), m = r & 2047;
        u16x8 zz = {};
        *(u16x8*)(kwp + ((long)b * PLP + j) * MD + m) = zz;
    } else {
        long flat = ((long)(bid - 312) * 256 + t) * 8;   // 2*2048*120
        int bm = (int)(flat / 120);
        int o = (int)(flat % 120);
        u16x8 zz = {};
        *(u16x8*)(vwpT + (long)bm * PLP + 1032 + o) = zz;
    }
}

__global__ void k_pooled(const float* __restrict__ x, const float* __restrict__ ew,
                         const float* __restrict__ tw, const float* __restrict__ aw,
                         float* __restrict__ dots) {
    int b = blockIdx.y;
    long base = (long)b * 1024 * MD;
    long start = (long)blockIdx.x * 8192;
    float s0 = 0, s1 = 0, s2 = 0;
    for (int s = 0; s < 32; ++s) {
        long f = start + threadIdx.x + (long)s * 256;
        float xv = x[base + f];
        int d = (int)(f & (MD - 1));
        s0 += xv * ew[d]; s1 += xv * tw[d]; s2 += xv * aw[d];
    }
    s0 = block_reduce_sum(s0);
    if (threadIdx.x == 0) atomicAdd(&dots[0 + b], s0);
    s1 = block_reduce_sum(s1);
    if (threadIdx.x == 0) atomicAdd(&dots[2 + b], s1);
    s2 = block_reduce_sum(s2);
    if (threadIdx.x == 0) atomicAdd(&dots[4 + b], s2);
}
__global__ void k_scal_fin(const float* __restrict__ dots, const float* __restrict__ eb,
                           const float* __restrict__ tb, const float* __restrict__ ab,
                           float* __restrict__ scal) {
    if (threadIdx.x == 0 && blockIdx.x == 0) {
        const float invL = 1.f / 1024.f;
        float e = 0, th = 0, al = 0;
        for (int b = 0; b < 2; ++b) {
            e  += sigm(dots[0 + b] * invL + eb[0]);
            th += sigm(dots[2 + b] * invL + tb[0]);
            al += sigm(dots[4 + b] * invL + ab[0]);
        }
        scal[0] = e * 0.5f; scal[1] = th * 0.5f; scal[2] = al * 0.5f;
    }
}

__global__ void k_silu8(const float* __restrict__ in, unsigned short* __restrict__ o) {
    long i = ((long)blockIdx.x * 256 + threadIdx.x) * 8;
    float4 a = *(const float4*)(in + i);
    float4 b = *(const float4*)(in + i + 4);
    u16x8 r;
    r[0] = f2bf(silu(a.x)); r[1] = f2bf(silu(a.y)); r[2] = f2bf(silu(a.z)); r[3] = f2bf(silu(a.w));
    r[4] = f2bf(silu(b.x)); r[5] = f2bf(silu(b.y)); r[6] = f2bf(silu(b.z)); r[7] = f2bf(silu(b.w));
    *(u16x8*)(o + i) = r;
}
// rg = bf16(ret + mlp2)
__global__ void k_addcvt(const float* __restrict__ a, const float* __restrict__ b,
                         unsigned short* __restrict__ o) {
    long i = ((long)blockIdx.x * 256 + threadIdx.x) * 8;
    float4 a0 = *(const float4*)(a + i), a1 = *(const float4*)(a + i + 4);
    float4 b0 = *(const float4*)(b + i), b1 = *(const float4*)(b + i + 4);
    u16x8 r;
    r[0] = f2bf(a0.x + b0.x); r[1] = f2bf(a0.y + b0.y); r[2] = f2bf(a0.z + b0.z); r[3] = f2bf(a0.w + b0.w);
    r[4] = f2bf(a1.x + b1.x); r[5] = f2bf(a1.y + b1.y); r[6] = f2bf(a1.z + b1.z); r[7] = f2bf(a1.w + b1.w);
    *(u16x8*)(o + i) = r;
}
// g = bf16(sigmoid(pre+gb) * (ret+mlp2))
__global__ void k_gate8(const float* __restrict__ pre, const float* __restrict__ gb,
                        const float* __restrict__ ret, const float* __restrict__ mlp2,
                        unsigned short* __restrict__ o) {
    long i = ((long)blockIdx.x * 256 + threadIdx.x) * 8;
    int m = (int)(i & (MD - 1));
    float4 p0 = *(const float4*)(pre + i),  p1 = *(const float4*)(pre + i + 4);
    float4 r0 = *(const float4*)(ret + i),  r1 = *(const float4*)(ret + i + 4);
    float4 q0 = *(const float4*)(mlp2 + i), q1 = *(const float4*)(mlp2 + i + 4);
    float4 g0 = *(const float4*)(gb + m),   g1 = *(const float4*)(gb + m + 4);
    u16x8 r;
    r[0] = f2bf(sigm(p0.x + g0.x) * (r0.x + q0.x));
    r[1] = f2bf(sigm(p0.y + g0.y) * (r0.y + q0.y));
    r[2] = f2bf(sigm(p0.z + g0.z) * (r0.z + q0.z));
    r[3] = f2bf(sigm(p0.w + g0.w) * (r0.w + q0.w));
    r[4] = f2bf(sigm(p1.x + g1.x) * (r1.x + q1.x));
    r[5] = f2bf(sigm(p1.y + g1.y) * (r1.y + q1.y));
    r[6] = f2bf(sigm(p1.z + g1.z) * (r1.z + q1.z));
    r[7] = f2bf(sigm(p1.w + g1.w) * (r1.w + q1.w));
    *(u16x8*)(o + i) = r;
}

__global__ void k_softmax(const float* __restrict__ S, unsigned short* __restrict__ attn) {
    int l = blockIdx.x, b = blockIdx.y;
    long base = ((long)b * 1024 + l) * PLP;
    int nvis = 8 + l + 1;
    const float scale = 0.022097086912079608f;  // 1/sqrt(2048)
    int t = threadIdx.x;
    float vals[5];
    float mx = -1e30f;
    #pragma unroll
    for (int s = 0; s < 5; ++s) {
        int j = t + s * 256;
        float v = -1e30f;
        if (j < nvis) v = S[base + j] * scale;
        vals[s] = v;
        mx = fmaxf(mx, v);
    }
    mx = block_reduce_max(mx);
    float sum = 0.f;
    #pragma unroll
    for (int s = 0; s < 5; ++s) {
        int j = t + s * 256;
        float e = 0.f;
        if (j < nvis) e = __expf(vals[s] - mx);
        vals[s] = e; sum += e;
    }
    sum = block_reduce_sum(sum);
    float inv = 1.f / sum;
    #pragma unroll
    for (int s = 0; s < 5; ++s) {
        int j = t + s * 256;
        if (j < PLP) attn[base + j] = f2bf(vals[s] * inv);
    }
}

__global__ void k_final(const float* __restrict__ x, const float* __restrict__ y,
                        const float* __restrict__ lnw, float* __restrict__ out) {
    int n = blockIdx.x;
    long base = (long)n * MD;
    int t = threadIdx.x;
    float4 a0 = *(const float4*)(x + base + t * 8), a1 = *(const float4*)(x + base + t * 8 + 4);
    float4 b0 = *(const float4*)(y + base + t * 8), b1 = *(const float4*)(y + base + t * 8 + 4);
    float v[8] = {a0.x + b0.x, a0.y + b0.y, a0.z + b0.z, a0.w + b0.w,
                  a1.x + b1.x, a1.y + b1.y, a1.z + b1.z, a1.w + b1.w};
    float ss = 0.f;
    #pragma unroll
    for (int e = 0; e < 8; ++e) ss += v[e] * v[e];
    ss = block_reduce_sum(ss);
    float inv = rsqrtf(ss * (1.f / 2048.f) + 1e-6f);
    float4 w0 = *(const float4*)(lnw + t * 8), w1 = *(const float4*)(lnw + t * 8 + 4);
    float4 o0 = {v[0] * inv * w0.x, v[1] * inv * w0.y, v[2] * inv * w0.z, v[3] * inv * w0.w};
    float4 o1 = {v[4] * inv * w1.x, v[5] * inv * w1.y, v[6] * inv * w1.z, v[7] * inv * w1.w};
    *(float4*)(out + base + t * 8) = o0;
    *(float4*)(out + base + t * 8 + 4) = o1;
}

// ---------------- host-side ----------------
static inline void gemm(hipStream_t st, const void* A, const void* B, void* C,
                        int Mc, int K, long sA, long sB, long sC,
                        int gx, int gy, int gz, int epi) {
    hipLaunchKernelGGL(gemm_nt, dim3(gx, gy, gz), dim3(256), 0, st,
                       (const unsigned short*)A, (const unsigned short*)B, C,
                       Mc, K, sA, sB, sC, epi);
}

extern "C" void kernel_launch(void* const* d_in, const int* in_sizes, int n_in,
                              void* d_out, int out_size, void* d_ws, size_t ws_size,
                              hipStream_t stream) {
    const float* x    = (const float*)d_in[0];
    const float* Wq   = (const float*)d_in[1];
    const float* Wk   = (const float*)d_in[2];
    const float* Wv   = (const float*)d_in[3];
    const float* qdw  = (const float*)d_in[4];
    const float* kdw  = (const float*)d_in[5];
    const float* vdw  = (const float*)d_in[6];
    const float* qpw  = (const float*)d_in[7];
    const float* kpw  = (const float*)d_in[8];
    const float* vpw  = (const float*)d_in[9];
    const float* pk   = (const float*)d_in[10];
    const float* pv   = (const float*)d_in[11];
    const float* mw1  = (const float*)d_in[12];
    const float* mw2  = (const float*)d_in[13];
    const float* etaw = (const float*)d_in[14];
    const float* etab = (const float*)d_in[15];
    const float* thw  = (const float*)d_in[16];
    const float* thb  = (const float*)d_in[17];
    const float* alw  = (const float*)d_in[18];
    const float* alb  = (const float*)d_in[19];
    const float* gw   = (const float*)d_in[20];
    const float* gb   = (const float*)d_in[21];
    const float* ow   = (const float*)d_in[22];
    const float* lnw  = (const float*)d_in[23];
    const float* mem  = (const float*)d_in[24];
    const float* sur  = (const float*)d_in[25];
    float* out = (float*)d_out;

    char* ws = (char*)d_ws;
    const size_t MB = 1024 * 1024;
    float* dots = (float*)ws;
    float* scal = (float*)(ws + 1024);
    // memory map (160 MB + 4 KB):
    float*          t0f  = (float*)(ws + 4096);                 // t_big[0..2], 48MB
    float*          t1f  = t0f + NM;
    float*          t2f  = t0f + 2 * NM;
    unsigned short* tproj = (unsigned short*)t0f;               // overlays t_big (24MB)
    float*          retf = (float*)(ws + 4096 + 48 * MB);       // 16MB
    unsigned short* k_bf = (unsigned short*)(ws + 4096 + 64 * MB);  // 8MB
    unsigned short* q_bf = k_bf + NM;                               // 8MB
    unsigned short* qc   = k_bf + 2 * NM;                           // 8MB (later rg)
    unsigned short* g_bf = k_bf;                                    // reuse after errT/kT
    unsigned short* x_bf = (unsigned short*)(ws + 4096 + 88 * MB);  // 8MB (later vf, attn)
    unsigned short* vf   = x_bf;
    unsigned short* attn = x_bf;
    unsigned short* wQKV = (unsigned short*)(ws + 4096 + 96 * MB);  // 24MB region E
    unsigned short* conv = wQKV;
    unsigned short* kwp  = wQKV;
    unsigned short* vwpT = kwp + (long)2 * PLP * MD;
    unsigned short* wPW  = (unsigned short*)(ws + 4096 + 120 * MB); // 24MB region F
    unsigned short* eT   = wPW;
    unsigned short* kT   = eT + NM;
    unsigned short* gw_bf = wPW;
    unsigned short* ow_bf = wPW + NM;
    unsigned short* wMem  = (unsigned short*)(ws + 4096 + 144 * MB); // 16MB region G
    unsigned short* wMlp1 = wMem + NM;
    unsigned short* wSnap = wMem;
    unsigned short* wMlp2 = wMem + NM;

    const dim3 b256(256);
    const dim3 bT(32, 8);

    // 1. scalars
    hipMemsetAsync(dots, 0, 256, stream);
    hipLaunchKernelGGL(k_pooled, dim3(256, 2), b256, 0, stream, x, etaw, thw, alw, dots);
    hipLaunchKernelGGL(k_scal_fin, dim3(1), dim3(64), 0, stream, dots, etab, thb, alb, scal);
    // 2. converts: x, Wq, Wk, Wv, qpw, kpw, vpw, mw1
    hipLaunchKernelGGL(k_cvt_multi, dim3(16384), b256, 0, stream,
                       x, Wq, Wk, Wv, qpw, kpw, vpw, mw1,
                       x_bf, wQKV, wQKV + NM, wQKV + 2 * (long)NM,
                       wPW, wPW + NM, wPW + 2 * (long)NM, wMlp1);
    // 3. mem -> wMem (transposed bf16)
    hipLaunchKernelGGL(k_transpose<float>, dim3(64, 64, 1), bT, 0, stream,
                       mem, wMem, MD, MD, MD, 0, 0L, 0L);
    // 4. G1: wide qkv projection -> tproj bf16 [2048][6144]
    gemm(stream, x_bf, wQKV, tproj, 6144, MD, 0, 0, 0, 96, 16, 1, 2);
    // 5. depthwise conv z3 -> conv
    hipLaunchKernelGGL(k_dwconv, dim3(6144), b256, 0, stream, tproj, qdw, kdw, vdw, conv);
    // 6. G2: pointwise z3 -> t_big fp32
    gemm(stream, conv, wPW, t0f, MD, MD, NM, NM, NM, 32, 16, 3, 0);
    // 7. misc (kwp p-rows, vwpT p-cols, zero tails) -- region E now free of conv
    hipLaunchKernelGGL(k_misc, dim3(552), b256, 0, stream, pk, pv, kwp, vwpT);
    // 8. post qkv: q_bf, k_bf(+kwp), vf
    hipLaunchKernelGGL(k_post_qkv, dim3(6144), b256, 0, stream, t0f, q_bf, k_bf, vf, kwp);
    // 9. vf -> vwpT (transposed, offset 8)
    hipLaunchKernelGGL(k_transpose<unsigned short>, dim3(64, 32, 2), bT, 0, stream,
                       vf, vwpT, 1024, MD, PLP, 8, (long)1024 * MD, (long)MD * PLP);
    // 10. G3 z2: pred = k.memT -> t0f ; mlp1 = q.w1T -> t1f
    gemm(stream, k_bf, wMem, t0f, MD, MD, NM, NM, NM, 32, 16, 2, 0);
    // 11. errT (vf - pred)^T -> eT ; kT -> kT
    hipLaunchKernelGGL(k_errT_kT, dim3(64, 64, 2), bT, 0, stream, vf, t0f, k_bf, eT);
    // 12. silu(mlp1) -> qc bf16
    hipLaunchKernelGGL(k_silu8, dim3(2048), b256, 0, stream, t1f, qc);
    // 13. G4: momT = eT.kT -> t2f
    gemm(stream, eT, kT, t2f, MD, MD, 0, 0, 0, 32, 16, 1, 0);
    // 14. snapT -> wSnap
    hipLaunchKernelGGL(k_snapT, dim3(64, 64), bT, 0, stream, mem, sur, t2f, scal, wSnap);
    // 15. converts: mw2, gw, ow (regions free after G3/G4)
    hipLaunchKernelGGL(k_cvt_multi, dim3(6144), b256, 0, stream,
                       mw2, gw, ow, mw2, mw2, mw2, mw2, mw2,
                       wMlp2, gw_bf, ow_bf, wMlp2, wMlp2, wMlp2, wMlp2, wMlp2);
    // 16. G5 z2: linret = q.snapT -> retf ; mlp2 = qc.wMlp2 -> t1f
    gemm(stream, q_bf, wSnap, retf, MD, MD, NM, NM, (long)(t1f - retf), 32, 16, 2, 0);
    // 17. G6: scores z2 -> t2f
    gemm(stream, q_bf, kwp, t2f, PLP, MD,
         (long)1024 * MD, (long)PLP * MD, (long)1024 * PLP, 18, 8, 2, 0);
    // 18. softmax -> attn bf16
    hipLaunchKernelGGL(k_softmax, dim3(1024, 2), b256, 0, stream, t2f, attn);
    // 19. G7: context z2 += retf
    gemm(stream, attn, vwpT, retf, MD, PLP,
         (long)1024 * PLP, (long)MD * PLP, (long)1024 * MD, 32, 8, 2, 1);
    // 20. rg = bf16(retf + mlp2) -> qc slot
    hipLaunchKernelGGL(k_addcvt, dim3(2048), b256, 0, stream, retf, t1f, qc);
    // 21. G8: gatepre = rg.gwT -> t0f
    gemm(stream, qc, gw_bf, t0f, MD, MD, 0, 0, 0, 32, 16, 1, 0);
    // 22. g = bf16(sigm(gatepre+gb)*(retf+mlp2)) -> g_bf (k_bf slot)
    hipLaunchKernelGGL(k_gate8, dim3(2048), b256, 0, stream, t0f, gb, retf, t1f, g_bf);
    // 23. G9: outproj = g.owT -> t0f
    gemm(stream, g_bf, ow_bf, t0f, MD, MD, 0, 0, 0, 32, 16, 1, 0);
    // 24. final RMSNorm
    hipLaunchKernelGGL(k_final, dim3(2048), b256, 0, stream, x, t0f, lnw, out);
}

// Round 4
// 785.893 us; speedup vs baseline: 1.4367x; 1.0203x over previous
//
#include <hip/hip_runtime.h>
#include <hip/hip_bf16.h>

// ---------------------------------------------------------------------------
// TitansMemory: B=2, L=1024, D=M=2048, P=8, Kconv=4.
// bf16 NT-GEMM, double-buffered global_load_lds (raw s_barrier + fine vmcnt),
// XOR-swizzled LDS. Two tiles: 128x128 (batched big GEMMs, >=512 blocks) and
// 128x64 (small/single GEMMs). Per-z epilogue nibbles fuse silu/bf16/accum.
// ---------------------------------------------------------------------------

#define NROWS 2048      // B*L
#define MD    2048      // D == M
#define PL    1032      // P + L
#define PLP   1152      // padded
#define NM    4194304   // 2048*2048

using bf16x8 = __attribute__((ext_vector_type(8))) __bf16;
using f32x4  = __attribute__((ext_vector_type(4))) float;
using u16x8  = __attribute__((ext_vector_type(8))) unsigned short;

__device__ __forceinline__ unsigned short f2bf(float f) {
    union { float f; unsigned int u; } c; c.f = f;
    unsigned int u = c.u;
    return (unsigned short)((u + 0x7fffu + ((u >> 16) & 1u)) >> 16);
}
__device__ __forceinline__ float bf2f(unsigned short h) {
    union { float f; unsigned int u; } c; c.u = ((unsigned int)h) << 16;
    return c.f;
}
__device__ __forceinline__ float ldf(const float* p) { return *p; }
__device__ __forceinline__ float ldf(const unsigned short* p) { return bf2f(*p); }
__device__ __forceinline__ float sigm(float x) { return 1.f / (1.f + __expf(-x)); }
__device__ __forceinline__ float silu(float x) { return x / (1.f + __expf(-x)); }

__device__ __forceinline__ float block_reduce_sum(float v) {
    __shared__ float ws[4];
    #pragma unroll
    for (int o = 32; o > 0; o >>= 1) v += __shfl_down(v, o);
    __syncthreads();
    if ((threadIdx.x & 63) == 0) ws[threadIdx.x >> 6] = v;
    __syncthreads();
    return (ws[0] + ws[1]) + (ws[2] + ws[3]);
}
__device__ __forceinline__ float block_reduce_max(float v) {
    __shared__ float wm[4];
    #pragma unroll
    for (int o = 32; o > 0; o >>= 1) v = fmaxf(v, __shfl_down(v, o));
    __syncthreads();
    if ((threadIdx.x & 63) == 0) wm[threadIdx.x >> 6] = v;
    __syncthreads();
    return fmaxf(fmaxf(wm[0], wm[1]), fmaxf(wm[2], wm[3]));
}

__device__ __forceinline__ void load_lds16(const unsigned short* g, unsigned short* l) {
    __builtin_amdgcn_global_load_lds(
        (const __attribute__((address_space(1))) unsigned int*)g,
        (__attribute__((address_space(3))) unsigned int*)l, 16, 0, 0);
}
__device__ __forceinline__ void raw_barrier() {
    __asm__ volatile("" ::: "memory");
    __builtin_amdgcn_s_barrier();
    __asm__ volatile("" ::: "memory");
}
__device__ __forceinline__ void epi_store(int epi, float* Cf, unsigned short* Ch,
                                          long off, float v) {
    if (epi == 0)      Cf[off] = v;
    else if (epi == 1) Cf[off] += v;
    else if (epi == 2) Ch[off] = f2bf(v);
    else               Ch[off] = f2bf(silu(v));
}

// ---------------- NT GEMM 128x64 tile (small/single GEMMs) ----------------
// C[n,m] = sum_k A[n,k]*B[m,k]. BK=64, dbuf, vmcnt(6) prefetch.
// epiPack: 4-bit epilogue code per blockIdx.z. sCb = C z-stride in BYTES.
__global__ __launch_bounds__(256) void gemm_nt(
    const unsigned short* __restrict__ A, const unsigned short* __restrict__ Bm,
    void* __restrict__ Cv, int Mc, int K, long sA, long sB, long sCb, int epiPack)
{
    __shared__ unsigned short As[2][8192];
    __shared__ unsigned short Bs[2][4096];
    const int tid = threadIdx.x, lane = tid & 63, w = tid >> 6;
    const int l16 = lane & 15, quad = lane >> 4;
    const int wr = (w >> 1) * 64, wc = (w & 1) * 32;
    const long rowBase = (long)blockIdx.y * 128;
    const long colBase = (long)blockIdx.x * 64;
    const unsigned short* Ap = A + (long)blockIdx.z * sA;
    const unsigned short* Bp = Bm + (long)blockIdx.z * sB;
    const int epi = (epiPack >> (blockIdx.z * 4)) & 15;
    const int r8 = lane >> 3;
    const int cg = (lane & 7) ^ r8;          // swizzled global 16B-chunk

    const unsigned short* gA[4]; const unsigned short* gB[2];
    unsigned short* lA[4]; unsigned short* lB[2];
    #pragma unroll
    for (int t = 0; t < 4; ++t) {
        int ch = w * 4 + t;
        gA[t] = Ap + (rowBase + ch * 8 + r8) * (long)K + cg * 8;
        lA[t] = &As[0][ch * 512];
    }
    #pragma unroll
    for (int t = 0; t < 2; ++t) {
        int ch = w * 2 + t;
        gB[t] = Bp + (colBase + ch * 8 + r8) * (long)K + cg * 8;
        lB[t] = &Bs[0][ch * 512];
    }

    f32x4 acc[4][2] = {};
    #pragma unroll
    for (int t = 0; t < 4; ++t) { load_lds16(gA[t], lA[t]); gA[t] += 64; }
    #pragma unroll
    for (int t = 0; t < 2; ++t) { load_lds16(gB[t], lB[t]); gB[t] += 64; }

    const int nIter = K >> 6;
    for (int it = 0; it < nIter; ++it) {
        const int cb = it & 1;
        if (it + 1 < nIter) {
            const int nb = cb ^ 1;
            #pragma unroll
            for (int t = 0; t < 4; ++t) { load_lds16(gA[t], lA[t] + nb * 8192); gA[t] += 64; }
            #pragma unroll
            for (int t = 0; t < 2; ++t) { load_lds16(gB[t], lB[t] + nb * 4096); gB[t] += 64; }
            __builtin_amdgcn_s_waitcnt(0xF76);   // vmcnt<=6
        } else {
            __builtin_amdgcn_s_waitcnt(0xF70);   // vmcnt(0)
        }
        raw_barrier();
        const unsigned short* Ac = As[cb];
        const unsigned short* Bc = Bs[cb];
        #pragma unroll
        for (int ks = 0; ks < 2; ++ks) {
            const int cl = ((ks * 4 + quad) ^ (l16 & 7)) * 8;
            bf16x8 af[4], bfr[2];
            #pragma unroll
            for (int i = 0; i < 4; ++i)
                af[i] = *(const bf16x8*)&Ac[(wr + i * 16 + l16) * 64 + cl];
            #pragma unroll
            for (int j = 0; j < 2; ++j)
                bfr[j] = *(const bf16x8*)&Bc[(wc + j * 16 + l16) * 64 + cl];
            #pragma unroll
            for (int i = 0; i < 4; ++i)
                #pragma unroll
                for (int j = 0; j < 2; ++j)
                    acc[i][j] = __builtin_amdgcn_mfma_f32_16x16x32_bf16(af[i], bfr[j], acc[i][j], 0, 0, 0);
        }
        raw_barrier();
    }

    char* Cb = (char*)Cv + (long)blockIdx.z * sCb;
    float* Cf = (float*)Cb;
    unsigned short* Ch = (unsigned short*)Cb;
    #pragma unroll
    for (int i = 0; i < 4; ++i)
        #pragma unroll
        for (int r = 0; r < 4; ++r) {
            long gr = rowBase + wr + i * 16 + quad * 4 + r;
            #pragma unroll
            for (int j = 0; j < 2; ++j) {
                long gc = colBase + wc + j * 16 + l16;
                epi_store(epi, Cf, Ch, gr * (long)Mc + gc, acc[i][j][r]);
            }
        }
}

// ---------------- NT GEMM 128x128 tile (batched big GEMMs) ----------------
// Wave tile 64x64 (4x4 frags), BK=64, dbuf (64KB LDS -> 2 blocks/CU),
// vmcnt(8) prefetch. 2x LDS arithmetic intensity vs 128x64.
__global__ __launch_bounds__(256) void gemm_nt_big(
    const unsigned short* __restrict__ A, const unsigned short* __restrict__ Bm,
    void* __restrict__ Cv, int Mc, int K, long sA, long sB, long sCb, int epiPack)
{
    __shared__ unsigned short As[2][8192];
    __shared__ unsigned short Bs[2][8192];
    const int tid = threadIdx.x, lane = tid & 63, w = tid >> 6;
    const int l16 = lane & 15, quad = lane >> 4;
    const int wr = (w >> 1) * 64, wc = (w & 1) * 64;
    const long rowBase = (long)blockIdx.y * 128;
    const long colBase = (long)blockIdx.x * 128;
    const unsigned short* Ap = A + (long)blockIdx.z * sA;
    const unsigned short* Bp = Bm + (long)blockIdx.z * sB;
    const int epi = (epiPack >> (blockIdx.z * 4)) & 15;
    const int r8 = lane >> 3;
    const int cg = (lane & 7) ^ r8;

    const unsigned short* gA[4]; const unsigned short* gB[4];
    unsigned short* lA[4]; unsigned short* lB[4];
    #pragma unroll
    for (int t = 0; t < 4; ++t) {
        int ch = w * 4 + t;                  // 16 chunks of 8 rows
        gA[t] = Ap + (rowBase + ch * 8 + r8) * (long)K + cg * 8;
        lA[t] = &As[0][ch * 512];
        gB[t] = Bp + (colBase + ch * 8 + r8) * (long)K + cg * 8;
        lB[t] = &Bs[0][ch * 512];
    }

    f32x4 acc[4][4] = {};
    #pragma unroll
    for (int t = 0; t < 4; ++t) { load_lds16(gA[t], lA[t]); gA[t] += 64; }
    #pragma unroll
    for (int t = 0; t < 4; ++t) { load_lds16(gB[t], lB[t]); gB[t] += 64; }

    const int nIter = K >> 6;
    for (int it = 0; it < nIter; ++it) {
        const int cb = it & 1;
        if (it + 1 < nIter) {
            const int nb = cb ^ 1;
            #pragma unroll
            for (int t = 0; t < 4; ++t) { load_lds16(gA[t], lA[t] + nb * 8192); gA[t] += 64; }
            #pragma unroll
            for (int t = 0; t < 4; ++t) { load_lds16(gB[t], lB[t] + nb * 8192); gB[t] += 64; }
            __builtin_amdgcn_s_waitcnt(0xF78);   // vmcnt<=8: current tile landed
        } else {
            __builtin_amdgcn_s_waitcnt(0xF70);   // vmcnt(0)
        }
        raw_barrier();
        const unsigned short* Ac = As[cb];
        const unsigned short* Bc = Bs[cb];
        #pragma unroll
        for (int ks = 0; ks < 2; ++ks) {
            const int cl = ((ks * 4 + quad) ^ (l16 & 7)) * 8;
            bf16x8 af[4], bfr[4];
            #pragma unroll
            for (int i = 0; i < 4; ++i)
                af[i] = *(const bf16x8*)&Ac[(wr + i * 16 + l16) * 64 + cl];
            #pragma unroll
            for (int j = 0; j < 4; ++j)
                bfr[j] = *(const bf16x8*)&Bc[(wc + j * 16 + l16) * 64 + cl];
            #pragma unroll
            for (int i = 0; i < 4; ++i)
                #pragma unroll
                for (int j = 0; j < 4; ++j)
                    acc[i][j] = __builtin_amdgcn_mfma_f32_16x16x32_bf16(af[i], bfr[j], acc[i][j], 0, 0, 0);
        }
        raw_barrier();
    }

    char* Cb = (char*)Cv + (long)blockIdx.z * sCb;
    float* Cf = (float*)Cb;
    unsigned short* Ch = (unsigned short*)Cb;
    #pragma unroll
    for (int i = 0; i < 4; ++i)
        #pragma unroll
        for (int r = 0; r < 4; ++r) {
            long gr = rowBase + wr + i * 16 + quad * 4 + r;
            #pragma unroll
            for (int j = 0; j < 4; ++j) {
                long gc = colBase + wc + j * 16 + l16;
                epi_store(epi, Cf, Ch, gr * (long)Mc + gc, acc[i][j][r]);
            }
        }
}

// ---------------- tiled transpose (+convert) to bf16, batched via z
template <typename TS>
__global__ void k_transpose(const TS* __restrict__ src, unsigned short* __restrict__ dst,
                            int R, int C, int dstLd, int dstOff, long sSrc, long sDst)
{
    __shared__ float tile[32][33];
    const TS* sp = src + (long)blockIdx.z * sSrc;
    unsigned short* dp = dst + (long)blockIdx.z * sDst;
    int c0 = blockIdx.x * 32, r0 = blockIdx.y * 32;
    int tx = threadIdx.x, ty = threadIdx.y;     // 32 x 8
    #pragma unroll
    for (int i = 0; i < 4; ++i)
        tile[ty + i * 8][tx] = ldf(&sp[(long)(r0 + ty + i * 8) * C + c0 + tx]);
    __syncthreads();
    #pragma unroll
    for (int i = 0; i < 4; ++i)
        dp[(long)(c0 + ty + i * 8) * dstLd + dstOff + r0 + tx] = f2bf(tile[tx][ty + i * 8]);
}

// z0: eT[m][n] = bf16(vf[n][m]-pred[n][m]); z1: kT[m][n] = k_bf[n][m]
__global__ void k_errT_kT(const unsigned short* __restrict__ vf, const float* __restrict__ pred,
                          const unsigned short* __restrict__ k_bf, unsigned short* __restrict__ eT)
{
    __shared__ float tile[32][33];
    int z = blockIdx.z;
    int c0 = blockIdx.x * 32, r0 = blockIdx.y * 32;
    int tx = threadIdx.x, ty = threadIdx.y;
    #pragma unroll
    for (int i = 0; i < 4; ++i) {
        long idx = (long)(r0 + ty + i * 8) * MD + c0 + tx;
        tile[ty + i * 8][tx] = (z == 0) ? (bf2f(vf[idx]) - pred[idx]) : bf2f(k_bf[idx]);
    }
    __syncthreads();
    unsigned short* dst = eT + (long)z * NM;
    #pragma unroll
    for (int i = 0; i < 4; ++i)
        dst[(long)(c0 + ty + i * 8) * MD + r0 + tx] = f2bf(tile[tx][ty + i * 8]);
}

// snapT[h][d] = bf16((1-a)*mem[d][h] + eta*sur[d][h] + (theta/2048)*momT[h][d])
__global__ void k_snapT(const float* __restrict__ mem, const float* __restrict__ sur,
                        const float* __restrict__ momT, const float* __restrict__ scal,
                        unsigned short* __restrict__ dst)
{
    __shared__ float tile[32][33];
    float eta = scal[0], theta = scal[1], alpha = scal[2];
    int h0 = blockIdx.y * 32, d0 = blockIdx.x * 32;
    int tx = threadIdx.x, ty = threadIdx.y;
    #pragma unroll
    for (int i = 0; i < 4; ++i) {
        long idx = (long)(d0 + ty + i * 8) * MD + h0 + tx;
        tile[ty + i * 8][tx] = (1.f - alpha) * mem[idx] + eta * sur[idx];
    }
    __syncthreads();
    #pragma unroll
    for (int i = 0; i < 4; ++i) {
        long oidx = (long)(h0 + ty + i * 8) * MD + d0 + tx;
        dst[oidx] = f2bf(tile[tx][ty + i * 8] + theta * (1.f / 2048.f) * momT[oidx]);
    }
}

// ---------------- fused / vectorized elementwise ----------------
__global__ void k_cvt_multi(const float* s0, const float* s1, const float* s2, const float* s3,
                            const float* s4, const float* s5, const float* s6, const float* s7,
                            unsigned short* d0, unsigned short* d1, unsigned short* d2, unsigned short* d3,
                            unsigned short* d4, unsigned short* d5, unsigned short* d6, unsigned short* d7)
{
    int seg = blockIdx.x >> 11;
    const float* s; unsigned short* d;
    switch (seg) {
        case 0: s = s0; d = d0; break;  case 1: s = s1; d = d1; break;
        case 2: s = s2; d = d2; break;  case 3: s = s3; d = d3; break;
        case 4: s = s4; d = d4; break;  case 5: s = s5; d = d5; break;
        case 6: s = s6; d = d6; break;  default: s = s7; d = d7; break;
    }
    long idx = ((long)(blockIdx.x & 2047) * 256 + threadIdx.x) * 8;
    float4 a = *(const float4*)(s + idx);
    float4 b = *(const float4*)(s + idx + 4);
    u16x8 o;
    o[0] = f2bf(a.x); o[1] = f2bf(a.y); o[2] = f2bf(a.z); o[3] = f2bf(a.w);
    o[4] = f2bf(b.x); o[5] = f2bf(b.y); o[6] = f2bf(b.z); o[7] = f2bf(b.w);
    *(u16x8*)(d + idx) = o;
}

// depthwise causal conv z3, vec8. tproj: [2048][6144] bf16; conv: [3][2048][2048]
__global__ void k_dwconv(const unsigned short* __restrict__ tproj,
                         const float* __restrict__ qdw, const float* __restrict__ kdw,
                         const float* __restrict__ vdw, unsigned short* __restrict__ conv)
{
    long u = (long)blockIdx.x * 256 + threadIdx.x;
    long flat = u * 8;
    int z = (int)(flat >> 22);
    int rem = (int)(flat & (NM - 1));
    int n = rem >> 11, m = rem & 2047;
    int l = n & 1023;
    const float* dw = (z == 0) ? qdw : (z == 1) ? kdw : vdw;
    const unsigned short* src = tproj + (long)n * 6144 + z * 2048 + m;
    float4 dwv[8];
    #pragma unroll
    for (int e = 0; e < 8; ++e) dwv[e] = *(const float4*)(dw + (m + e) * 4);
    float acc[8] = {};
    #pragma unroll
    for (int j = 0; j < 4; ++j) {
        int dl = j - 3;
        if (l + dl >= 0) {
            u16x8 r = *(const u16x8*)(src + (long)dl * 6144);
            #pragma unroll
            for (int e = 0; e < 8; ++e)
                acc[e] += ((const float*)&dwv[e])[j] * bf2f(r[e]);
        }
    }
    u16x8 o;
    #pragma unroll
    for (int e = 0; e < 8; ++e) o[e] = f2bf(acc[e]);
    *(u16x8*)(conv + (long)z * NM + (long)n * 2048 + m) = o;
}

// post-pointwise: z0/z1: silu+l2n -> q_bf / (k_bf + kwp); z2: silu -> vf
__global__ void k_post_qkv(const float* __restrict__ t_big, unsigned short* __restrict__ q_bf,
                           unsigned short* __restrict__ k_bf, unsigned short* __restrict__ vf,
                           unsigned short* __restrict__ kwp)
{
    int bid = blockIdx.x, z = bid >> 11, n = bid & 2047;
    const float* row = t_big + (long)z * NM + (long)n * 2048;
    int t = threadIdx.x;
    float4 a = *(const float4*)(row + t * 8);
    float4 b = *(const float4*)(row + t * 8 + 4);
    float v[8] = {silu(a.x), silu(a.y), silu(a.z), silu(a.w),
                  silu(b.x), silu(b.y), silu(b.z), silu(b.w)};
    if (z == 2) {
        u16x8 o;
        #pragma unroll
        for (int e = 0; e < 8; ++e) o[e] = f2bf(v[e]);
        *(u16x8*)(vf + (long)n * 2048 + t * 8) = o;
        return;
    }
    float ss = 0.f;
    #pragma unroll
    for (int e = 0; e < 8; ++e) ss += v[e] * v[e];
    ss = block_reduce_sum(ss);
    float inv = 1.f / (sqrtf(ss) + 1e-6f);
    u16x8 o;
    #pragma unroll
    for (int e = 0; e < 8; ++e) o[e] = f2bf(v[e] * inv);
    if (z == 0) {
        *(u16x8*)(q_bf + (long)n * 2048 + t * 8) = o;
    } else {
        *(u16x8*)(k_bf + (long)n * 2048 + t * 8) = o;
        int bb = n >> 10, l = n & 1023;
        *(u16x8*)(kwp + ((long)bb * PLP + 8 + l) * MD + t * 8) = o;
    }
}

// misc: pkn rows (8) | pv->vwpT (64) | kwp tail zero (240) | vwpT tail zero (240)
__global__ void k_misc(const float* __restrict__ pk, const float* __restrict__ pv,
                       unsigned short* __restrict__ kwp, unsigned short* __restrict__ vwpT)
{
    int bid = blockIdx.x, t = threadIdx.x;
    if (bid < 8) {
        const float* row = pk + bid * MD;
        float4 a = *(const float4*)(row + t * 8);
        float4 b = *(const float4*)(row + t * 8 + 4);
        float v[8] = {a.x, a.y, a.z, a.w, b.x, b.y, b.z, b.w};
        float ss = 0.f;
        #pragma unroll
        for (int e = 0; e < 8; ++e) ss += v[e] * v[e];
        ss = block_reduce_sum(ss);
        float inv = 1.f / (sqrtf(ss) + 1e-6f);
        u16x8 o;
        #pragma unroll
        for (int e = 0; e < 8; ++e) o[e] = f2bf(v[e] * inv);
        *(u16x8*)(kwp + (long)bid * MD + t * 8) = o;
        *(u16x8*)(kwp + (long)PLP * MD + (long)bid * MD + t * 8) = o;
    } else if (bid < 72) {
        int i = (bid - 8) * 256 + t;         // 16384 = 2048*8
        int m = i >> 3, pp = i & 7;
        unsigned short h = f2bf(pv[pp * MD + m]);
        vwpT[(long)m * PLP + pp] = h;
        vwpT[(long)MD * PLP + (long)m * PLP + pp] = h;
    } else if (bid < 312) {
        long flat = ((long)(bid - 72) * 256 + t) * 8;    // 2*120*2048
        int b = (int)(flat / 245760);
        int r = (int)(flat % 245760);
        int j = 1032 + (r >> 11), m = r & 2047;
        u16x8 zz = {};
        *(u16x8*)(kwp + ((long)b * PLP + j) * MD + m) = zz;
    } else {
        long flat = ((long)(bid - 312) * 256 + t) * 8;   // 2*2048*120
        int bm = (int)(flat / 120);
        int o = (int)(flat % 120);
        u16x8 zz = {};
        *(u16x8*)(vwpT + (long)bm * PLP + 1032 + o) = zz;
    }
}

__global__ void k_pooled(const float* __restrict__ x, const float* __restrict__ ew,
                         const float* __restrict__ tw, const float* __restrict__ aw,
                         float* __restrict__ dots) {
    int b = blockIdx.y;
    long base = (long)b * 1024 * MD;
    long start = (long)blockIdx.x * 8192;
    float s0 = 0, s1 = 0, s2 = 0;
    for (int s = 0; s < 32; ++s) {
        long f = start + threadIdx.x + (long)s * 256;
        float xv = x[base + f];
        int d = (int)(f & (MD - 1));
        s0 += xv * ew[d]; s1 += xv * tw[d]; s2 += xv * aw[d];
    }
    s0 = block_reduce_sum(s0);
    if (threadIdx.x == 0) atomicAdd(&dots[0 + b], s0);
    s1 = block_reduce_sum(s1);
    if (threadIdx.x == 0) atomicAdd(&dots[2 + b], s1);
    s2 = block_reduce_sum(s2);
    if (threadIdx.x == 0) atomicAdd(&dots[4 + b], s2);
}
__global__ void k_scal_fin(const float* __restrict__ dots, const float* __restrict__ eb,
                           const float* __restrict__ tb, const float* __restrict__ ab,
                           float* __restrict__ scal) {
    if (threadIdx.x == 0 && blockIdx.x == 0) {
        const float invL = 1.f / 1024.f;
        float e = 0, th = 0, al = 0;
        for (int b = 0; b < 2; ++b) {
            e  += sigm(dots[0 + b] * invL + eb[0]);
            th += sigm(dots[2 + b] * invL + tb[0]);
            al += sigm(dots[4 + b] * invL + ab[0]);
        }
        scal[0] = e * 0.5f; scal[1] = th * 0.5f; scal[2] = al * 0.5f;
    }
}

// rg = bf16(ret + mlp2)
__global__ void k_addcvt(const float* __restrict__ a, const float* __restrict__ b,
                         unsigned short* __restrict__ o) {
    long i = ((long)blockIdx.x * 256 + threadIdx.x) * 8;
    float4 a0 = *(const float4*)(a + i), a1 = *(const float4*)(a + i + 4);
    float4 b0 = *(const float4*)(b + i), b1 = *(const float4*)(b + i + 4);
    u16x8 r;
    r[0] = f2bf(a0.x + b0.x); r[1] = f2bf(a0.y + b0.y); r[2] = f2bf(a0.z + b0.z); r[3] = f2bf(a0.w + b0.w);
    r[4] = f2bf(a1.x + b1.x); r[5] = f2bf(a1.y + b1.y); r[6] = f2bf(a1.z + b1.z); r[7] = f2bf(a1.w + b1.w);
    *(u16x8*)(o + i) = r;
}
// g = bf16(sigmoid(pre+gb) * (ret+mlp2))
__global__ void k_gate8(const float* __restrict__ pre, const float* __restrict__ gb,
                        const float* __restrict__ ret, const float* __restrict__ mlp2,
                        unsigned short* __restrict__ o) {
    long i = ((long)blockIdx.x * 256 + threadIdx.x) * 8;
    int m = (int)(i & (MD - 1));
    float4 p0 = *(const float4*)(pre + i),  p1 = *(const float4*)(pre + i + 4);
    float4 r0 = *(const float4*)(ret + i),  r1 = *(const float4*)(ret + i + 4);
    float4 q0 = *(const float4*)(mlp2 + i), q1 = *(const float4*)(mlp2 + i + 4);
    float4 g0 = *(const float4*)(gb + m),   g1 = *(const float4*)(gb + m + 4);
    u16x8 r;
    r[0] = f2bf(sigm(p0.x + g0.x) * (r0.x + q0.x));
    r[1] = f2bf(sigm(p0.y + g0.y) * (r0.y + q0.y));
    r[2] = f2bf(sigm(p0.z + g0.z) * (r0.z + q0.z));
    r[3] = f2bf(sigm(p0.w + g0.w) * (r0.w + q0.w));
    r[4] = f2bf(sigm(p1.x + g1.x) * (r1.x + q1.x));
    r[5] = f2bf(sigm(p1.y + g1.y) * (r1.y + q1.y));
    r[6] = f2bf(sigm(p1.z + g1.z) * (r1.z + q1.z));
    r[7] = f2bf(sigm(p1.w + g1.w) * (r1.w + q1.w));
    *(u16x8*)(o + i) = r;
}

__global__ void k_softmax(const float* __restrict__ S, unsigned short* __restrict__ attn) {
    int l = blockIdx.x, b = blockIdx.y;
    long base = ((long)b * 1024 + l) * PLP;
    int nvis = 8 + l + 1;
    const float scale = 0.022097086912079608f;  // 1/sqrt(2048)
    int t = threadIdx.x;
    float vals[5];
    float mx = -1e30f;
    #pragma unroll
    for (int s = 0; s < 5; ++s) {
        int j = t + s * 256;
        float v = -1e30f;
        if (j < nvis) v = S[base + j] * scale;
        vals[s] = v;
        mx = fmaxf(mx, v);
    }
    mx = block_reduce_max(mx);
    float sum = 0.f;
    #pragma unroll
    for (int s = 0; s < 5; ++s) {
        int j = t + s * 256;
        float e = 0.f;
        if (j < nvis) e = __expf(vals[s] - mx);
        vals[s] = e; sum += e;
    }
    sum = block_reduce_sum(sum);
    float inv = 1.f / sum;
    #pragma unroll
    for (int s = 0; s < 5; ++s) {
        int j = t + s * 256;
        if (j < PLP) attn[base + j] = f2bf(vals[s] * inv);
    }
}

__global__ void k_final(const float* __restrict__ x, const float* __restrict__ y,
                        const float* __restrict__ lnw, float* __restrict__ out) {
    int n = blockIdx.x;
    long base = (long)n * MD;
    int t = threadIdx.x;
    float4 a0 = *(const float4*)(x + base + t * 8), a1 = *(const float4*)(x + base + t * 8 + 4);
    float4 b0 = *(const float4*)(y + base + t * 8), b1 = *(const float4*)(y + base + t * 8 + 4);
    float v[8] = {a0.x + b0.x, a0.y + b0.y, a0.z + b0.z, a0.w + b0.w,
                  a1.x + b1.x, a1.y + b1.y, a1.z + b1.z, a1.w + b1.w};
    float ss = 0.f;
    #pragma unroll
    for (int e = 0; e < 8; ++e) ss += v[e] * v[e];
    ss = block_reduce_sum(ss);
    float inv = rsqrtf(ss * (1.f / 2048.f) + 1e-6f);
    float4 w0 = *(const float4*)(lnw + t * 8), w1 = *(const float4*)(lnw + t * 8 + 4);
    float4 o0 = {v[0] * inv * w0.x, v[1] * inv * w0.y, v[2] * inv * w0.z, v[3] * inv * w0.w};
    float4 o1 = {v[4] * inv * w1.x, v[5] * inv * w1.y, v[6] * inv * w1.z, v[7] * inv * w1.w};
    *(float4*)(out + base + t * 8) = o0;
    *(float4*)(out + base + t * 8 + 4) = o1;
}

// ---------------- host-side ----------------
static inline void gemm64(hipStream_t st, const void* A, const void* B, void* C,
                          int Mc, int K, long sA, long sB, long sCb,
                          int gx, int gy, int gz, int epiPack) {
    hipLaunchKernelGGL(gemm_nt, dim3(gx, gy, gz), dim3(256), 0, st,
                       (const unsigned short*)A, (const unsigned short*)B, C,
                       Mc, K, sA, sB, sCb, epiPack);
}
static inline void gemm128(hipStream_t st, const void* A, const void* B, void* C,
                           int Mc, int K, long sA, long sB, long sCb,
                           int gx, int gy, int gz, int epiPack) {
    hipLaunchKernelGGL(gemm_nt_big, dim3(gx, gy, gz), dim3(256), 0, st,
                       (const unsigned short*)A, (const unsigned short*)B, C,
                       Mc, K, sA, sB, sCb, epiPack);
}

extern "C" void kernel_launch(void* const* d_in, const int* in_sizes, int n_in,
                              void* d_out, int out_size, void* d_ws, size_t ws_size,
                              hipStream_t stream) {
    const float* x    = (const float*)d_in[0];
    const float* Wq   = (const float*)d_in[1];
    const float* Wk   = (const float*)d_in[2];
    const float* Wv   = (const float*)d_in[3];
    const float* qdw  = (const float*)d_in[4];
    const float* kdw  = (const float*)d_in[5];
    const float* vdw  = (const float*)d_in[6];
    const float* qpw  = (const float*)d_in[7];
    const float* kpw  = (const float*)d_in[8];
    const float* vpw  = (const float*)d_in[9];
    const float* pk   = (const float*)d_in[10];
    const float* pv   = (const float*)d_in[11];
    const float* mw1  = (const float*)d_in[12];
    const float* mw2  = (const float*)d_in[13];
    const float* etaw = (const float*)d_in[14];
    const float* etab = (const float*)d_in[15];
    const float* thw  = (const float*)d_in[16];
    const float* thb  = (const float*)d_in[17];
    const float* alw  = (const float*)d_in[18];
    const float* alb  = (const float*)d_in[19];
    const float* gw   = (const float*)d_in[20];
    const float* gb   = (const float*)d_in[21];
    const float* ow   = (const float*)d_in[22];
    const float* lnw  = (const float*)d_in[23];
    const float* mem  = (const float*)d_in[24];
    const float* sur  = (const float*)d_in[25];
    float* out = (float*)d_out;

    char* ws = (char*)d_ws;
    const size_t MB = 1024 * 1024;
    float* dots = (float*)ws;
    float* scal = (float*)(ws + 1024);
    // memory map (160 MB + 4 KB):
    float*          t0f  = (float*)(ws + 4096);                 // t_big[0..2], 48MB
    float*          t1f  = t0f + NM;
    float*          t2f  = t0f + 2 * NM;
    unsigned short* tproj = (unsigned short*)t0f;               // overlays t_big (24MB)
    float*          retf = (float*)(ws + 4096 + 48 * MB);       // 16MB
    unsigned short* k_bf = (unsigned short*)(ws + 4096 + 64 * MB);  // 8MB
    unsigned short* q_bf = k_bf + NM;                               // 8MB
    unsigned short* qc   = k_bf + 2 * NM;                           // 8MB (silu(mlp1), later rg)
    unsigned short* g_bf = k_bf;                                    // reuse after errT/kT
    unsigned short* x_bf = (unsigned short*)(ws + 4096 + 88 * MB);  // 8MB (later vf, attn)
    unsigned short* vf   = x_bf;
    unsigned short* attn = x_bf;
    unsigned short* wQKV = (unsigned short*)(ws + 4096 + 96 * MB);  // 24MB region E
    unsigned short* conv = wQKV;
    unsigned short* kwp  = wQKV;
    unsigned short* vwpT = kwp + (long)2 * PLP * MD;
    unsigned short* wPW  = (unsigned short*)(ws + 4096 + 120 * MB); // 24MB region F
    unsigned short* eT   = wPW;
    unsigned short* kT   = eT + NM;
    unsigned short* gw_bf = wPW;
    unsigned short* ow_bf = wPW + NM;
    unsigned short* wMem  = (unsigned short*)(ws + 4096 + 144 * MB); // 16MB region G
    unsigned short* wMlp1 = wMem + NM;
    unsigned short* wSnap = wMem;
    unsigned short* wMlp2 = wMem + NM;

    const dim3 b256(256);
    const dim3 bT(32, 8);

    // 1. scalars
    hipMemsetAsync(dots, 0, 256, stream);
    hipLaunchKernelGGL(k_pooled, dim3(256, 2), b256, 0, stream, x, etaw, thw, alw, dots);
    hipLaunchKernelGGL(k_scal_fin, dim3(1), dim3(64), 0, stream, dots, etab, thb, alb, scal);
    // 2. converts: x, Wq, Wk, Wv, qpw, kpw, vpw, mw1
    hipLaunchKernelGGL(k_cvt_multi, dim3(16384), b256, 0, stream,
                       x, Wq, Wk, Wv, qpw, kpw, vpw, mw1,
                       x_bf, wQKV, wQKV + NM, wQKV + 2 * (long)NM,
                       wPW, wPW + NM, wPW + 2 * (long)NM, wMlp1);
    // 3. mem -> wMem (transposed bf16)
    hipLaunchKernelGGL(k_transpose<float>, dim3(64, 64, 1), bT, 0, stream,
                       mem, wMem, MD, MD, MD, 0, 0L, 0L);
    // 4. G1 big: wide qkv projection -> tproj bf16 [2048][6144]
    gemm128(stream, x_bf, wQKV, tproj, 6144, MD, 0, 0, 0, 48, 16, 1, 2);
    // 5. depthwise conv z3 -> conv
    hipLaunchKernelGGL(k_dwconv, dim3(6144), b256, 0, stream, tproj, qdw, kdw, vdw, conv);
    // 6. G2 big: pointwise z3 -> t_big fp32
    gemm128(stream, conv, wPW, t0f, MD, MD, NM, NM, (long)NM * 4, 16, 16, 3, 0);
    // 7. misc (kwp p-rows, vwpT p-cols, zero tails)
    hipLaunchKernelGGL(k_misc, dim3(552), b256, 0, stream, pk, pv, kwp, vwpT);
    // 8. post qkv: q_bf, k_bf(+kwp), vf
    hipLaunchKernelGGL(k_post_qkv, dim3(6144), b256, 0, stream, t0f, q_bf, k_bf, vf, kwp);
    // 9. vf -> vwpT (transposed, offset 8)
    hipLaunchKernelGGL(k_transpose<unsigned short>, dim3(64, 32, 2), bT, 0, stream,
                       vf, vwpT, 1024, MD, PLP, 8, (long)1024 * MD, (long)MD * PLP);
    // 10. G3 big z2: pred = k.memT -> t0f f32 ; mlp1 = q.w1T -> silu bf16 -> qc
    gemm128(stream, k_bf, wMem, t0f, MD, MD, NM, NM,
            (long)((char*)qc - (char*)t0f), 16, 16, 2, 0x30);
    // 11. errT (vf - pred)^T -> eT ; kT -> kT
    hipLaunchKernelGGL(k_errT_kT, dim3(64, 64, 2), bT, 0, stream, vf, t0f, k_bf, eT);
    // 12. G4: momT = eT.kT -> t2f
    gemm64(stream, eT, kT, t2f, MD, MD, 0, 0, 0, 32, 16, 1, 0);
    // 13. snapT -> wSnap
    hipLaunchKernelGGL(k_snapT, dim3(64, 64), bT, 0, stream, mem, sur, t2f, scal, wSnap);
    // 14. converts: mw2, gw, ow
    hipLaunchKernelGGL(k_cvt_multi, dim3(6144), b256, 0, stream,
                       mw2, gw, ow, mw2, mw2, mw2, mw2, mw2,
                       wMlp2, gw_bf, ow_bf, wMlp2, wMlp2, wMlp2, wMlp2, wMlp2);
    // 15. G5 big z2: linret = q.snapT -> retf ; mlp2 = qc.wMlp2 -> t1f
    gemm128(stream, q_bf, wSnap, retf, MD, MD, NM, NM,
            (long)((char*)t1f - (char*)retf), 16, 16, 2, 0);
    // 16. G6: scores z2 -> t2f
    gemm64(stream, q_bf, kwp, t2f, PLP, MD,
           (long)1024 * MD, (long)PLP * MD, (long)1024 * PLP * 4, 18, 8, 2, 0);
    // 17. softmax -> attn bf16
    hipLaunchKernelGGL(k_softmax, dim3(1024, 2), b256, 0, stream, t2f, attn);
    // 18. G7: context z2 += retf
    gemm64(stream, attn, vwpT, retf, MD, PLP,
           (long)1024 * PLP, (long)MD * PLP, (long)1024 * MD * 4, 32, 8, 2, 0x11);
    // 19. rg = bf16(retf + mlp2) -> qc slot
    hipLaunchKernelGGL(k_addcvt, dim3(2048), b256, 0, stream, retf, t1f, qc);
    // 20. G8: gatepre = rg.gwT -> t0f
    gemm64(stream, qc, gw_bf, t0f, MD, MD, 0, 0, 0, 32, 16, 1, 0);
    // 21. g = bf16(sigm(gatepre+gb)*(retf+mlp2)) -> g_bf
    hipLaunchKernelGGL(k_gate8, dim3(2048), b256, 0, stream, t0f, gb, retf, t1f, g_bf);
    // 22. G9: outproj = g.owT -> t0f
    gemm64(stream, g_bf, ow_bf, t0f, MD, MD, 0, 0, 0, 32, 16, 1, 0);
    // 23. final RMSNorm
    hipLaunchKernelGGL(k_final, dim3(2048), b256, 0, stream, x, t0f, lnw, out);
}